// Round 2
// baseline (614.238 us; speedup 1.0000x reference)
//
#include <hip/hip_runtime.h>
#include <hip/hip_bf16.h>
#include <cstdint>
#include <cstddef>

// Problem constants
#define B_ 8
#define S_ 1024
#define H_ 16
#define E_ 64
#define D_ 1024      // embed dim
#define M_ (B_ * S_) // 8192 rows of x

typedef unsigned short u16;
typedef short s16x8 __attribute__((ext_vector_type(8)));
typedef float f32x4 __attribute__((ext_vector_type(4)));

// fp32 -> bf16, round-to-nearest-even
__device__ __forceinline__ u16 f2b(float f) {
  union { float f; unsigned u; } v; v.f = f;
  unsigned u = v.u;
  return (u16)((u + 0x7FFFu + ((u >> 16) & 1u)) >> 16);
}

// async global->LDS, 16B per lane. LDS dest is wave-uniform base + lane*16.
__device__ __forceinline__ void gload16(const void* g, void* lds) {
  __builtin_amdgcn_global_load_lds(
      (const __attribute__((address_space(1))) void*)g,
      (__attribute__((address_space(3))) void*)lds, 16, 0, 0);
}

// ---------------- kernel 1: x fp32 -> bf16 ----------------
__global__ void k_cvt_x(const float* __restrict__ x, u16* __restrict__ xb) {
  size_t i = ((size_t)blockIdx.x * 256 + threadIdx.x) * 8;
  float4 a = *(const float4*)(x + i);
  float4 b = *(const float4*)(x + i + 4);
  uint4 o;
  o.x = f2b(a.x) | ((unsigned)f2b(a.y) << 16);
  o.y = f2b(a.z) | ((unsigned)f2b(a.w) << 16);
  o.z = f2b(b.x) | ((unsigned)f2b(b.y) << 16);
  o.w = f2b(b.z) | ((unsigned)f2b(b.w) << 16);
  *(uint4*)(xb + i) = o;
}

// ---------------- kernel 2: build WbT[n][k] bf16 (n = mat*1024 + h*64 + e, k = d)
// LDS tile transpose so both global read (along e) and write (along d) are coalesced.
__global__ void k_build_wbt(const float* __restrict__ Wq, const float* __restrict__ Wk,
                            const float* __restrict__ Wv, u16* __restrict__ wbt) {
  __shared__ u16 T[64][65];
  int d0 = blockIdx.x * 64;          // 16 d-tiles
  int mh = blockIdx.y;               // 48 = 3 mats * 16 heads
  int mat = mh >> 4, h = mh & 15;
  const float* W = (mat == 0) ? Wq : (mat == 1) ? Wk : Wv;
  int tid = threadIdx.x;
#pragma unroll
  for (int rep = 0; rep < 4; rep++) {
    int dl = rep * 16 + (tid >> 4);
    int e0 = (tid & 15) * 4;
    float4 v = *(const float4*)(W + (size_t)h * (D_ * E_) + (size_t)(d0 + dl) * E_ + e0);
    T[dl][e0] = f2b(v.x); T[dl][e0 + 1] = f2b(v.y);
    T[dl][e0 + 2] = f2b(v.z); T[dl][e0 + 3] = f2b(v.w);
  }
  __syncthreads();
#pragma unroll
  for (int rep = 0; rep < 4; rep++) {
    int el = rep * 16 + (tid >> 4);
    int dl0 = (tid & 15) * 4;
    ushort4 o;
    o.x = T[dl0][el]; o.y = T[dl0 + 1][el]; o.z = T[dl0 + 2][el]; o.w = T[dl0 + 3][el];
    int n = mat * 1024 + h * 64 + el;
    *(ushort4*)(wbt + (size_t)n * D_ + d0 + dl0) = o;
  }
}

// ---------------- kernel 3: QKV GEMM ----------------
// C[m][n] = xb[m][:] . WbT[n][:]  (both row-major over k), 128x128 tile, BK=64,
// 4 waves (2x2), each 64x64 via 16x16x32 bf16 MFMA. global_load_lds w=16 with
// XOR chunk swizzle applied on the GLOBAL source (LDS dest linear, guide m173).
__global__ __launch_bounds__(256) void k_qkv(
    const u16* __restrict__ xb, const u16* __restrict__ wbt,
    const float* __restrict__ bq, const float* __restrict__ bk, const float* __restrict__ bv,
    u16* __restrict__ Qb, u16* __restrict__ Kb, u16* __restrict__ Vb) {
  __shared__ u16 As[128 * 64];
  __shared__ u16 Bs[128 * 64];
  int tid = threadIdx.x, l = tid & 63, w = tid >> 6;
  int m0 = blockIdx.y * 128, n0 = blockIdx.x * 128;
  int wm = w >> 1, wn = w & 1;
  int rl = l & 15, kg = l >> 4;
  f32x4 acc[4][4] = {};
  for (int k0 = 0; k0 < D_; k0 += 64) {
#pragma unroll
    for (int i = 0; i < 4; i++) {
      int ci = w * 4 + i;                 // 0..15, each inst covers 8 rows (128B/row)
      int r = ci * 8 + (l >> 3);
      int c = (l & 7) ^ (r & 7);          // pre-swizzled source chunk
      gload16(xb  + (size_t)(m0 + r) * D_ + k0 + c * 8, (char*)As + ci * 1024);
      gload16(wbt + (size_t)(n0 + r) * D_ + k0 + c * 8, (char*)Bs + ci * 1024);
    }
    __syncthreads();
#pragma unroll
    for (int kk = 0; kk < 2; kk++) {
      s16x8 af[4], bfr[4];
      int chunk = kk * 4 + kg;
#pragma unroll
      for (int fm = 0; fm < 4; fm++) {
        int r = wm * 64 + fm * 16 + rl;
        af[fm] = *(const s16x8*)(As + r * 64 + ((chunk ^ (r & 7)) * 8));
      }
#pragma unroll
      for (int fn = 0; fn < 4; fn++) {
        int r = wn * 64 + fn * 16 + rl;
        bfr[fn] = *(const s16x8*)(Bs + r * 64 + ((chunk ^ (r & 7)) * 8));
      }
#pragma unroll
      for (int fm = 0; fm < 4; fm++)
#pragma unroll
        for (int fn = 0; fn < 4; fn++)
          acc[fm][fn] = __builtin_amdgcn_mfma_f32_16x16x32_bf16(af[fm], bfr[fn], acc[fm][fn], 0, 0, 0);
    }
    __syncthreads();
  }
  // epilogue: +bias, ->bf16, scatter to Q/K/V [h][b][s][e]
#pragma unroll
  for (int fn = 0; fn < 4; fn++) {
    int n = n0 + wn * 64 + fn * 16 + rl;
    int mat = n >> 10, h = (n >> 6) & 15, e = n & 63;
    const float* bias = (mat == 0) ? bq : (mat == 1) ? bk : bv;
    float bval = bias[h * 64 + e];
    u16* dst = (mat == 0) ? Qb : (mat == 1) ? Kb : Vb;
#pragma unroll
    for (int fm = 0; fm < 4; fm++)
#pragma unroll
      for (int j = 0; j < 4; j++) {
        int m = m0 + wm * 64 + fm * 16 + kg * 4 + j;
        int bb = m >> 10, s = m & 1023;
        dst[(size_t)((h * B_ + bb) * S_ + s) * E_ + e] = f2b(acc[fm][fn][j] + bval);
      }
  }
}

// ---------------- kernel 4: Vb[h][b][s][e] -> Vt[h][b][e][s] ----------------
__global__ void k_vt(const u16* __restrict__ Vb, u16* __restrict__ Vt) {
  __shared__ u16 T[64][65];
  int hb = blockIdx.y, s0 = blockIdx.x * 64, tid = threadIdx.x;
  const u16* src = Vb + (size_t)hb * (S_ * E_);
#pragma unroll
  for (int rep = 0; rep < 4; rep++) {
    int sl = rep * 16 + (tid >> 4);
    int e0 = (tid & 15) * 4;
    ushort4 v = *(const ushort4*)(src + (size_t)(s0 + sl) * E_ + e0);
    T[sl][e0] = v.x; T[sl][e0 + 1] = v.y; T[sl][e0 + 2] = v.z; T[sl][e0 + 3] = v.w;
  }
  __syncthreads();
  u16* dst = Vt + (size_t)hb * (S_ * E_);
#pragma unroll
  for (int rep = 0; rep < 4; rep++) {
    int el = rep * 16 + (tid >> 4);
    int sl0 = (tid & 15) * 4;
    ushort4 o;
    o.x = T[sl0][el]; o.y = T[sl0 + 1][el]; o.z = T[sl0 + 2][el]; o.w = T[sl0 + 3][el];
    *(ushort4*)(dst + (size_t)el * S_ + s0 + sl0) = o;
  }
}

// ---------------- kernel 5: scores = Q K^T / 32 -> att region (fp32) ----------------
__global__ __launch_bounds__(256) void k_scores(
    const u16* __restrict__ Qb, const u16* __restrict__ Kb, float* __restrict__ att) {
  __shared__ u16 Qs[128 * 64];
  __shared__ u16 Ks[128 * 64];
  int tid = threadIdx.x, l = tid & 63, w = tid >> 6;
  int hb = blockIdx.z, m0 = blockIdx.y * 128, n0 = blockIdx.x * 128;
  const u16* Qp = Qb + (size_t)hb * (S_ * E_);
  const u16* Kp = Kb + (size_t)hb * (S_ * E_);
#pragma unroll
  for (int i = 0; i < 4; i++) {
    int ci = w * 4 + i;
    int r = ci * 8 + (l >> 3);
    int c = (l & 7) ^ (r & 7);
    gload16(Qp + (size_t)(m0 + r) * E_ + c * 8, (char*)Qs + ci * 1024);
    gload16(Kp + (size_t)(n0 + r) * E_ + c * 8, (char*)Ks + ci * 1024);
  }
  __syncthreads();
  int wm = w >> 1, wn = w & 1, rl = l & 15, kg = l >> 4;
  f32x4 acc[4][4] = {};
#pragma unroll
  for (int kk = 0; kk < 2; kk++) {
    s16x8 af[4], bfr[4];
    int chunk = kk * 4 + kg;
#pragma unroll
    for (int fm = 0; fm < 4; fm++) {
      int r = wm * 64 + fm * 16 + rl;
      af[fm] = *(const s16x8*)(Qs + r * 64 + ((chunk ^ (r & 7)) * 8));
    }
#pragma unroll
    for (int fn = 0; fn < 4; fn++) {
      int r = wn * 64 + fn * 16 + rl;
      bfr[fn] = *(const s16x8*)(Ks + r * 64 + ((chunk ^ (r & 7)) * 8));
    }
#pragma unroll
    for (int fm = 0; fm < 4; fm++)
#pragma unroll
      for (int fn = 0; fn < 4; fn++)
        acc[fm][fn] = __builtin_amdgcn_mfma_f32_16x16x32_bf16(af[fm], bfr[fn], acc[fm][fn], 0, 0, 0);
  }
  float* out = att + ((size_t)hb << 20);
#pragma unroll
  for (int fm = 0; fm < 4; fm++)
#pragma unroll
    for (int j = 0; j < 4; j++) {
      int s = m0 + wm * 64 + fm * 16 + kg * 4 + j;
#pragma unroll
      for (int fn = 0; fn < 4; fn++) {
        int t = n0 + wn * 64 + fn * 16 + rl;
        out[((size_t)s << 10) + t] = acc[fm][fn][j] * 0.03125f;
      }
    }
}

// ---------------- kernel 6: thresholded softmax, in place, 1 row per wave ----------------
__global__ __launch_bounds__(256) void k_softmax(float* __restrict__ att) {
  int tid = threadIdx.x, l = tid & 63, w = tid >> 6;
  size_t row = (size_t)blockIdx.x * 4 + w;
  float* p = att + (row << 10);
  float4 v[4];
#pragma unroll
  for (int i = 0; i < 4; i++) v[i] = *(const float4*)(p + l * 4 + i * 256);
  float m = -1e30f;
#pragma unroll
  for (int i = 0; i < 4; i++)
    m = fmaxf(m, fmaxf(fmaxf(v[i].x, v[i].y), fmaxf(v[i].z, v[i].w)));
#pragma unroll
  for (int off = 32; off > 0; off >>= 1) m = fmaxf(m, __shfl_xor(m, off));
  float Z = 0.f;
#pragma unroll
  for (int i = 0; i < 4; i++) {
    v[i].x = __expf(v[i].x - m); v[i].y = __expf(v[i].y - m);
    v[i].z = __expf(v[i].z - m); v[i].w = __expf(v[i].w - m);
    Z += v[i].x + v[i].y + v[i].z + v[i].w;
  }
#pragma unroll
  for (int off = 32; off > 0; off >>= 1) Z += __shfl_xor(Z, off);
  // keep p >= 0.001  <=>  e >= 0.001 * Z
  float thr = 0.001f * Z;
  float Z2 = 0.f;
#pragma unroll
  for (int i = 0; i < 4; i++) {
    v[i].x = (v[i].x >= thr) ? v[i].x : 0.f;
    v[i].y = (v[i].y >= thr) ? v[i].y : 0.f;
    v[i].z = (v[i].z >= thr) ? v[i].z : 0.f;
    v[i].w = (v[i].w >= thr) ? v[i].w : 0.f;
    Z2 += v[i].x + v[i].y + v[i].z + v[i].w;
  }
#pragma unroll
  for (int off = 32; off > 0; off >>= 1) Z2 += __shfl_xor(Z2, off);
  float inv = 1.f / (Z2 + 1e-12f * Z);   // att = e/(Z2 + 1e-12*Z)
#pragma unroll
  for (int i = 0; i < 4; i++) {
    v[i].x *= inv; v[i].y *= inv; v[i].z *= inv; v[i].w *= inv;
    *(float4*)(p + l * 4 + i * 256) = v[i];
  }
}

// ---------------- kernel 7: latent = att @ V; out = x + concat(latent) ----------------
__global__ __launch_bounds__(256) void k_pv(
    const float* __restrict__ att, const u16* __restrict__ Vt,
    const float* __restrict__ x, float* __restrict__ out) {
  __shared__ u16 As[128 * 64];  // att tile [s 128][t 64] bf16, XOR-swizzled chunks
  __shared__ u16 Bs[64 * 64];   // Vt tile [e 64][t 64] bf16
  int tid = threadIdx.x, l = tid & 63, w = tid >> 6;
  int hb = blockIdx.y, m0 = blockIdx.x * 128;
  int h = hb >> 3, bb = hb & 7;
  const float* ap = att + ((size_t)hb << 20);
  const u16* vp = Vt + (size_t)hb * (S_ * E_);
  int rl = l & 15, kg = l >> 4;
  f32x4 acc[2][4] = {};
  for (int t0 = 0; t0 < S_; t0 += 64) {
    {  // stage att (fp32 -> bf16, reg-staged so we can swizzle the ds_write)
      int r = tid >> 1;
      int half = tid & 1;
      const float* src = ap + ((size_t)(m0 + r) << 10) + t0 + half * 32;
#pragma unroll
      for (int j = 0; j < 8; j++) {  // 8 x float4 -> 8 x 8B
        float4 v = *(const float4*)(src + j * 4);
        uint2 o;
        o.x = f2b(v.x) | ((unsigned)f2b(v.y) << 16);
        o.y = f2b(v.z) | ((unsigned)f2b(v.w) << 16);
        int c = half * 4 + (j >> 1);      // logical 16B chunk in row
        int sub = (j & 1) * 8;
        *(uint2*)((char*)As + r * 128 + ((c ^ (r & 7)) * 16) + sub) = o;
      }
    }
#pragma unroll
    for (int i = 0; i < 2; i++) {  // stage Vt tile via global_load_lds
      int ci = w * 2 + i;
      int r = ci * 8 + (l >> 3);
      int c = (l & 7) ^ (r & 7);
      gload16(vp + (size_t)r * S_ + t0 + c * 8, (char*)Bs + ci * 1024);
    }
    __syncthreads();
#pragma unroll
    for (int kk = 0; kk < 2; kk++) {
      s16x8 af[2], bfr[4];
      int chunk = kk * 4 + kg;
#pragma unroll
      for (int fm = 0; fm < 2; fm++) {
        int r = w * 32 + fm * 16 + rl;
        af[fm] = *(const s16x8*)(As + r * 64 + ((chunk ^ (r & 7)) * 8));
      }
#pragma unroll
      for (int fn = 0; fn < 4; fn++) {
        int r = fn * 16 + rl;
        bfr[fn] = *(const s16x8*)(Bs + r * 64 + ((chunk ^ (r & 7)) * 8));
      }
#pragma unroll
      for (int fm = 0; fm < 2; fm++)
#pragma unroll
        for (int fn = 0; fn < 4; fn++)
          acc[fm][fn] = __builtin_amdgcn_mfma_f32_16x16x32_bf16(af[fm], bfr[fn], acc[fm][fn], 0, 0, 0);
    }
    __syncthreads();
  }
#pragma unroll
  for (int fm = 0; fm < 2; fm++)
#pragma unroll
    for (int j = 0; j < 4; j++) {
      int s = m0 + w * 32 + fm * 16 + kg * 4 + j;
#pragma unroll
      for (int fn = 0; fn < 4; fn++) {
        int e = fn * 16 + rl;
        size_t idx = ((size_t)(bb * S_ + s) << 10) + h * 64 + e;
        out[idx] = x[idx] + acc[fm][fn][j];
      }
    }
}

extern "C" void kernel_launch(void* const* d_in, const int* in_sizes, int n_in,
                              void* d_out, int out_size, void* d_ws, size_t ws_size,
                              hipStream_t stream) {
  const float* x  = (const float*)d_in[0];
  const float* Wq = (const float*)d_in[1];
  const float* bq = (const float*)d_in[2];
  const float* Wk = (const float*)d_in[3];
  const float* bk = (const float*)d_in[4];
  const float* Wv = (const float*)d_in[5];
  const float* bv = (const float*)d_in[6];
  float* xres = (float*)d_out;
  float* att  = xres + (size_t)B_ * S_ * D_;  // 8,388,608 floats in

  // workspace layout (needs 70 MB); Vt reuses the xb slot (xb dead after k_qkv)
  char* ws = (char*)d_ws;
  u16* xb  = (u16*)(ws);                  // 16 MB
  u16* wbt = (u16*)(ws + 16777216);       //  6 MB
  u16* Qb  = (u16*)(ws + 23068672);       // 16 MB
  u16* Kb  = (u16*)(ws + 39845888);       // 16 MB
  u16* Vb  = (u16*)(ws + 56623104);       // 16 MB  (total 70 MB)
  u16* Vt  = (u16*)(ws);                  // aliases xb, written after k_qkv

  k_cvt_x   <<<dim3(4096),       dim3(256), 0, stream>>>(x, xb);
  k_build_wbt<<<dim3(16, 48),    dim3(256), 0, stream>>>(Wq, Wk, Wv, wbt);
  k_qkv     <<<dim3(24, 64),     dim3(256), 0, stream>>>(xb, wbt, bq, bk, bv, Qb, Kb, Vb);
  k_vt      <<<dim3(16, 128),    dim3(256), 0, stream>>>(Vb, Vt);
  k_scores  <<<dim3(8, 8, 128),  dim3(256), 0, stream>>>(Qb, Kb, att);
  k_softmax <<<dim3(32768),      dim3(256), 0, stream>>>(att);
  k_pv      <<<dim3(8, 128),     dim3(256), 0, stream>>>(att, Vt, x, xres);
}

// Round 3
// 592.616 us; speedup vs baseline: 1.0365x; 1.0365x over previous
//
#include <hip/hip_runtime.h>
#include <hip/hip_bf16.h>
#include <cstdint>
#include <cstddef>

// Problem constants
#define B_ 8
#define S_ 1024
#define H_ 16
#define E_ 64
#define D_ 1024      // embed dim
#define NCH 16       // 1024 / 64 t-chunks

typedef unsigned short u16;
typedef short s16x8 __attribute__((ext_vector_type(8)));
typedef float f32x4 __attribute__((ext_vector_type(4)));

// fp32 -> bf16, round-to-nearest-even
__device__ __forceinline__ u16 f2b(float f) {
  union { float f; unsigned u; } v; v.f = f;
  unsigned u = v.u;
  return (u16)((u + 0x7FFFu + ((u >> 16) & 1u)) >> 16);
}

// async global->LDS, 16B per lane. LDS dest is wave-uniform base + lane*16.
__device__ __forceinline__ void gload16(const void* g, void* lds) {
  __builtin_amdgcn_global_load_lds(
      (const __attribute__((address_space(1))) void*)g,
      (__attribute__((address_space(3))) void*)lds, 16, 0, 0);
}

// ---------------- kernel 1: x fp32 -> bf16 ----------------
__global__ void k_cvt_x(const float* __restrict__ x, u16* __restrict__ xb) {
  size_t i = ((size_t)blockIdx.x * 256 + threadIdx.x) * 8;
  float4 a = *(const float4*)(x + i);
  float4 b = *(const float4*)(x + i + 4);
  uint4 o;
  o.x = f2b(a.x) | ((unsigned)f2b(a.y) << 16);
  o.y = f2b(a.z) | ((unsigned)f2b(a.w) << 16);
  o.z = f2b(b.x) | ((unsigned)f2b(b.y) << 16);
  o.w = f2b(b.z) | ((unsigned)f2b(b.w) << 16);
  *(uint4*)(xb + i) = o;
}

// ---------------- kernel 2: build WbT[n][k] bf16 (n = mat*1024 + h*64 + e, k = d)
__global__ void k_build_wbt(const float* __restrict__ Wq, const float* __restrict__ Wk,
                            const float* __restrict__ Wv, u16* __restrict__ wbt) {
  __shared__ u16 T[64][65];
  int d0 = blockIdx.x * 64;
  int mh = blockIdx.y;
  int mat = mh >> 4, h = mh & 15;
  const float* W = (mat == 0) ? Wq : (mat == 1) ? Wk : Wv;
  int tid = threadIdx.x;
#pragma unroll
  for (int rep = 0; rep < 4; rep++) {
    int dl = rep * 16 + (tid >> 4);
    int e0 = (tid & 15) * 4;
    float4 v = *(const float4*)(W + (size_t)h * (D_ * E_) + (size_t)(d0 + dl) * E_ + e0);
    T[dl][e0] = f2b(v.x); T[dl][e0 + 1] = f2b(v.y);
    T[dl][e0 + 2] = f2b(v.z); T[dl][e0 + 3] = f2b(v.w);
  }
  __syncthreads();
#pragma unroll
  for (int rep = 0; rep < 4; rep++) {
    int el = rep * 16 + (tid >> 4);
    int dl0 = (tid & 15) * 4;
    ushort4 o;
    o.x = T[dl0][el]; o.y = T[dl0 + 1][el]; o.z = T[dl0 + 2][el]; o.w = T[dl0 + 3][el];
    int n = mat * 1024 + h * 64 + el;
    *(ushort4*)(wbt + (size_t)n * D_ + d0 + dl0) = o;
  }
}

// ---------------- kernel 3: QKV GEMM (unchanged, proven) ----------------
__global__ __launch_bounds__(256) void k_qkv(
    const u16* __restrict__ xb, const u16* __restrict__ wbt,
    const float* __restrict__ bq, const float* __restrict__ bk, const float* __restrict__ bv,
    u16* __restrict__ Qb, u16* __restrict__ Kb, u16* __restrict__ Vb) {
  __shared__ u16 As[128 * 64];
  __shared__ u16 Bs[128 * 64];
  int tid = threadIdx.x, l = tid & 63, w = tid >> 6;
  int m0 = blockIdx.y * 128, n0 = blockIdx.x * 128;
  int wm = w >> 1, wn = w & 1;
  int rl = l & 15, kg = l >> 4;
  f32x4 acc[4][4] = {};
  for (int k0 = 0; k0 < D_; k0 += 64) {
#pragma unroll
    for (int i = 0; i < 4; i++) {
      int ci = w * 4 + i;
      int r = ci * 8 + (l >> 3);
      int c = (l & 7) ^ (r & 7);
      gload16(xb  + (size_t)(m0 + r) * D_ + k0 + c * 8, (char*)As + ci * 1024);
      gload16(wbt + (size_t)(n0 + r) * D_ + k0 + c * 8, (char*)Bs + ci * 1024);
    }
    __syncthreads();
#pragma unroll
    for (int kk = 0; kk < 2; kk++) {
      s16x8 af[4], bfr[4];
      int chunk = kk * 4 + kg;
#pragma unroll
      for (int fm = 0; fm < 4; fm++) {
        int r = wm * 64 + fm * 16 + rl;
        af[fm] = *(const s16x8*)(As + r * 64 + ((chunk ^ (r & 7)) * 8));
      }
#pragma unroll
      for (int fn = 0; fn < 4; fn++) {
        int r = wn * 64 + fn * 16 + rl;
        bfr[fn] = *(const s16x8*)(Bs + r * 64 + ((chunk ^ (r & 7)) * 8));
      }
#pragma unroll
      for (int fm = 0; fm < 4; fm++)
#pragma unroll
        for (int fn = 0; fn < 4; fn++)
          acc[fm][fn] = __builtin_amdgcn_mfma_f32_16x16x32_bf16(af[fm], bfr[fn], acc[fm][fn], 0, 0, 0);
    }
    __syncthreads();
  }
#pragma unroll
  for (int fn = 0; fn < 4; fn++) {
    int n = n0 + wn * 64 + fn * 16 + rl;
    int mat = n >> 10, h = (n >> 6) & 15, e = n & 63;
    const float* bias = (mat == 0) ? bq : (mat == 1) ? bk : bv;
    float bval = bias[h * 64 + e];
    u16* dst = (mat == 0) ? Qb : (mat == 1) ? Kb : Vb;
#pragma unroll
    for (int fm = 0; fm < 4; fm++)
#pragma unroll
      for (int j = 0; j < 4; j++) {
        int m = m0 + wm * 64 + fm * 16 + kg * 4 + j;
        int bb = m >> 10, s = m & 1023;
        dst[(size_t)((h * B_ + bb) * S_ + s) * E_ + e] = f2b(acc[fm][fn][j] + bval);
      }
  }
}

// ---------------- kernel 4: Vb[h][b][s][e] -> Vt[h][b][e][s] ----------------
__global__ void k_vt(const u16* __restrict__ Vb, u16* __restrict__ Vt) {
  __shared__ u16 T[64][65];
  int hb = blockIdx.y, s0 = blockIdx.x * 64, tid = threadIdx.x;
  const u16* src = Vb + (size_t)hb * (S_ * E_);
#pragma unroll
  for (int rep = 0; rep < 4; rep++) {
    int sl = rep * 16 + (tid >> 4);
    int e0 = (tid & 15) * 4;
    ushort4 v = *(const ushort4*)(src + (size_t)(s0 + sl) * E_ + e0);
    T[sl][e0] = v.x; T[sl][e0 + 1] = v.y; T[sl][e0 + 2] = v.z; T[sl][e0 + 3] = v.w;
  }
  __syncthreads();
  u16* dst = Vt + (size_t)hb * (S_ * E_);
#pragma unroll
  for (int rep = 0; rep < 4; rep++) {
    int el = rep * 16 + (tid >> 4);
    int sl0 = (tid & 15) * 4;
    ushort4 o;
    o.x = T[sl0][el]; o.y = T[sl0 + 1][el]; o.z = T[sl0 + 2][el]; o.w = T[sl0 + 3][el];
    *(ushort4*)(dst + (size_t)el * S_ + s0 + sl0) = o;
  }
}

// ---------------- kernel 5: fused scores + thresholded softmax + PV + residual ----
// One block = 32 q-rows of one (h,b). Scores kept in registers acc[2][16] (f32x4).
// K streamed through 16KB LDS dbuf. att written to HBM once; bf16 copy fed to PV
// via swizzled LDS chunks. 4 waves: QK cols split 16/wave/chunk; PV quadrants 16x32.
__global__ __launch_bounds__(256) void f_attn(
    const u16* __restrict__ Qb, const u16* __restrict__ Kb, const u16* __restrict__ Vt,
    const float* __restrict__ x, float* __restrict__ att, float* __restrict__ out) {
  __shared__ u16 Qlds[32 * 64];        // 4 KB
  __shared__ u16 Kc[2][64 * 64];       // 16 KB dbuf
  __shared__ u16 Ab[2][32 * 64];       // 8 KB dbuf (att bf16 chunk)
  __shared__ u16 Vc[2][64 * 64];       // 16 KB dbuf
  __shared__ float red[3][32][4];      // cross-wave reduce

  // XCD-chunked swizzle: 4096 blocks, 512 per XCD -> all 32 m-blocks of an
  // (h,b) land on one XCD (K/V panels L2-resident once per XCD).
  int p = blockIdx.x;
  int L = (p & 7) * 512 + (p >> 3);
  int hb = L >> 5, mblk = L & 31;
  int m0 = mblk * 32;
  int tid = threadIdx.x, l = tid & 63, w = tid >> 6;
  int rl = l & 15, kg = l >> 4;

  const u16* Qp = Qb + (size_t)hb * (S_ * E_) + (size_t)m0 * E_;
  const u16* Kp = Kb + (size_t)hb * (S_ * E_);
  const u16* Vp = Vt + (size_t)hb * (S_ * E_);

  // ---- prologue: stage Q tile (32x64) + K chunk 0 ----
  {
    int r = w * 8 + (l >> 3), c = (l & 7) ^ (r & 7);
    gload16(Qp + (size_t)r * E_ + c * 8, (char*)Qlds + w * 1024);
  }
#pragma unroll
  for (int i = 0; i < 2; i++) {
    int ci = w * 2 + i;
    int r = ci * 8 + (l >> 3), c = (l & 7) ^ (r & 7);
    gload16(Kp + (size_t)r * E_ + c * 8, (char*)Kc[0] + ci * 1024);
  }
  __syncthreads();

  s16x8 af[2][2];
#pragma unroll
  for (int fm = 0; fm < 2; fm++)
#pragma unroll
    for (int kk = 0; kk < 2; kk++) {
      int r = fm * 16 + rl, ch = kk * 4 + kg;
      af[fm][kk] = *(const s16x8*)((const char*)Qlds + r * 128 + ((ch ^ (r & 7)) * 16));
    }

  f32x4 acc[2][NCH];
#pragma unroll
  for (int fm = 0; fm < 2; fm++)
#pragma unroll
    for (int ct = 0; ct < NCH; ct++)
#pragma unroll
      for (int j = 0; j < 4; j++) acc[fm][ct][j] = 0.f;

  // ---- QK^T: chunk ct covers K rows (score cols) ct*64..ct*64+63.
  // acc[fm][ct][j] = scores[16fm + 4kg + j][ct*64 + 16w + rl]
#pragma unroll
  for (int ct = 0; ct < NCH; ct++) {
    if (ct + 1 < NCH) {
#pragma unroll
      for (int i = 0; i < 2; i++) {
        int ci = w * 2 + i;
        int r = ci * 8 + (l >> 3), c = (l & 7) ^ (r & 7);
        gload16(Kp + (size_t)((ct + 1) * 64 + r) * E_ + c * 8,
                (char*)Kc[(ct + 1) & 1] + ci * 1024);
      }
    }
    s16x8 bf[2];
#pragma unroll
    for (int kk = 0; kk < 2; kk++) {
      int r = w * 16 + rl, ch = kk * 4 + kg;
      bf[kk] = *(const s16x8*)((const char*)Kc[ct & 1] + r * 128 + ((ch ^ (r & 7)) * 16));
    }
#pragma unroll
    for (int fm = 0; fm < 2; fm++)
#pragma unroll
      for (int kk = 0; kk < 2; kk++)
        acc[fm][ct] = __builtin_amdgcn_mfma_f32_16x16x32_bf16(af[fm][kk], bf[kk], acc[fm][ct], 0, 0, 0);
    __syncthreads();
  }

  // ---- softmax over each row (scale 1/32 folded into exp) ----
  float mx[2][4], Z[2][4], Z2[2][4];
#pragma unroll
  for (int fm = 0; fm < 2; fm++)
#pragma unroll
    for (int j = 0; j < 4; j++) {
      float m = acc[fm][0][j];
#pragma unroll
      for (int ct = 1; ct < NCH; ct++) m = fmaxf(m, acc[fm][ct][j]);
#pragma unroll
      for (int off = 8; off >= 1; off >>= 1) m = fmaxf(m, __shfl_xor(m, off));
      mx[fm][j] = m;
    }
  if (rl == 0) {
#pragma unroll
    for (int fm = 0; fm < 2; fm++)
#pragma unroll
      for (int j = 0; j < 4; j++) red[0][fm * 16 + kg * 4 + j][w] = mx[fm][j];
  }
  __syncthreads();
#pragma unroll
  for (int fm = 0; fm < 2; fm++)
#pragma unroll
    for (int j = 0; j < 4; j++) {
      f32x4 r4 = *(const f32x4*)&red[0][fm * 16 + kg * 4 + j][0];
      mx[fm][j] = fmaxf(fmaxf(r4[0], r4[1]), fmaxf(r4[2], r4[3]));
    }
#pragma unroll
  for (int fm = 0; fm < 2; fm++)
#pragma unroll
    for (int j = 0; j < 4; j++) {
      float s = 0.f;
#pragma unroll
      for (int ct = 0; ct < NCH; ct++) {
        float e = __expf((acc[fm][ct][j] - mx[fm][j]) * 0.03125f);
        acc[fm][ct][j] = e;
        s += e;
      }
#pragma unroll
      for (int off = 8; off >= 1; off >>= 1) s += __shfl_xor(s, off);
      Z[fm][j] = s;
    }
  if (rl == 0) {
#pragma unroll
    for (int fm = 0; fm < 2; fm++)
#pragma unroll
      for (int j = 0; j < 4; j++) red[1][fm * 16 + kg * 4 + j][w] = Z[fm][j];
  }
  __syncthreads();
#pragma unroll
  for (int fm = 0; fm < 2; fm++)
#pragma unroll
    for (int j = 0; j < 4; j++) {
      f32x4 r4 = *(const f32x4*)&red[1][fm * 16 + kg * 4 + j][0];
      Z[fm][j] = r4[0] + r4[1] + r4[2] + r4[3];
    }
  // threshold: keep e >= 0.001*Z  (<=> p >= 0.001), re-sum survivors
#pragma unroll
  for (int fm = 0; fm < 2; fm++)
#pragma unroll
    for (int j = 0; j < 4; j++) {
      float thr = 0.001f * Z[fm][j];
      float s = 0.f;
#pragma unroll
      for (int ct = 0; ct < NCH; ct++) {
#pragma unroll
        for (int q = 0; q < 1; q++) {}  // keep loop structure flat
        float e = acc[fm][ct][j];
        e = (e >= thr) ? e : 0.f;
        acc[fm][ct][j] = e;
        s += e;
      }
#pragma unroll
      for (int off = 8; off >= 1; off >>= 1) s += __shfl_xor(s, off);
      Z2[fm][j] = s;
    }
  if (rl == 0) {
#pragma unroll
    for (int fm = 0; fm < 2; fm++)
#pragma unroll
      for (int j = 0; j < 4; j++) red[2][fm * 16 + kg * 4 + j][w] = Z2[fm][j];
  }
  __syncthreads();
#pragma unroll
  for (int fm = 0; fm < 2; fm++)
#pragma unroll
    for (int j = 0; j < 4; j++) {
      f32x4 r4 = *(const f32x4*)&red[2][fm * 16 + kg * 4 + j][0];
      float z2 = r4[0] + r4[1] + r4[2] + r4[3];
      float inv = 1.f / (z2 + 1e-12f * Z[fm][j]);  // == p/(sum_kept_p + 1e-12)
#pragma unroll
      for (int ct = 0; ct < NCH; ct++) acc[fm][ct][j] *= inv;
    }

  // ---- PV + att store, chunked. Wave quadrant: rows mh*16.., cols e nh*32.. ----
  int mh = w >> 1, nh = w & 1;
  f32x4 acc2[2];
#pragma unroll
  for (int fn = 0; fn < 2; fn++)
#pragma unroll
    for (int j = 0; j < 4; j++) acc2[fn][j] = 0.f;
  float* attp = att + ((size_t)hb << 20) + ((size_t)m0 << 10);

#pragma unroll
  for (int ct = 0; ct < NCH; ct++) {
    // write att bf16 chunk into Ab (swizzled) + fp32 to HBM
#pragma unroll
    for (int fm = 0; fm < 2; fm++)
#pragma unroll
      for (int j = 0; j < 4; j++) {
        int m = fm * 16 + kg * 4 + j;
        int tl = w * 16 + rl;
        float v = acc[fm][ct][j];
        int cch = (tl >> 3) ^ (m & 7);
        *(u16*)((char*)Ab[ct & 1] + m * 128 + cch * 16 + (tl & 7) * 2) = f2b(v);
        attp[((size_t)m << 10) + ct * 64 + tl] = v;
      }
    // stage Vt chunk [e 64][t 64]
#pragma unroll
    for (int i = 0; i < 2; i++) {
      int ci = w * 2 + i;
      int r = ci * 8 + (l >> 3), c = (l & 7) ^ (r & 7);
      gload16(Vp + (size_t)r * S_ + ct * 64 + c * 8, (char*)Vc[ct & 1] + ci * 1024);
    }
    __syncthreads();
    s16x8 a2[2], b2[2][2];
#pragma unroll
    for (int kk = 0; kk < 2; kk++) {
      int ch = kk * 4 + kg;
      int r = mh * 16 + rl;
      a2[kk] = *(const s16x8*)((const char*)Ab[ct & 1] + r * 128 + ((ch ^ (r & 7)) * 16));
#pragma unroll
      for (int fn = 0; fn < 2; fn++) {
        int rv = nh * 32 + fn * 16 + rl;
        b2[fn][kk] = *(const s16x8*)((const char*)Vc[ct & 1] + rv * 128 + ((ch ^ (rv & 7)) * 16));
      }
    }
#pragma unroll
    for (int fn = 0; fn < 2; fn++)
#pragma unroll
      for (int kk = 0; kk < 2; kk++)
        acc2[fn] = __builtin_amdgcn_mfma_f32_16x16x32_bf16(a2[kk], b2[fn][kk], acc2[fn], 0, 0, 0);
  }

  // ---- epilogue: out = x + latent ----
  int h = hb >> 3, bb = hb & 7;
#pragma unroll
  for (int fn = 0; fn < 2; fn++)
#pragma unroll
    for (int j = 0; j < 4; j++) {
      int m = m0 + mh * 16 + kg * 4 + j;
      int e = h * 64 + nh * 32 + fn * 16 + rl;
      size_t idx = (((size_t)bb * S_ + m) << 10) + e;
      out[idx] = x[idx] + acc2[fn][j];
    }
}

extern "C" void kernel_launch(void* const* d_in, const int* in_sizes, int n_in,
                              void* d_out, int out_size, void* d_ws, size_t ws_size,
                              hipStream_t stream) {
  const float* x  = (const float*)d_in[0];
  const float* Wq = (const float*)d_in[1];
  const float* bq = (const float*)d_in[2];
  const float* Wk = (const float*)d_in[3];
  const float* bk = (const float*)d_in[4];
  const float* Wv = (const float*)d_in[5];
  const float* bv = (const float*)d_in[6];
  float* xres = (float*)d_out;
  float* att  = xres + (size_t)B_ * S_ * D_;

  char* ws = (char*)d_ws;
  u16* xb  = (u16*)(ws);                  // 16 MB
  u16* wbt = (u16*)(ws + 16777216);       //  6 MB
  u16* Qb  = (u16*)(ws + 23068672);       // 16 MB
  u16* Kb  = (u16*)(ws + 39845888);       // 16 MB
  u16* Vb  = (u16*)(ws + 56623104);       // 16 MB
  u16* Vt  = (u16*)(ws);                  // aliases xb (dead after k_qkv)

  k_cvt_x    <<<dim3(4096),    dim3(256), 0, stream>>>(x, xb);
  k_build_wbt<<<dim3(16, 48),  dim3(256), 0, stream>>>(Wq, Wk, Wv, wbt);
  k_qkv      <<<dim3(24, 64),  dim3(256), 0, stream>>>(xb, wbt, bq, bk, bv, Qb, Kb, Vb);
  k_vt       <<<dim3(16, 128), dim3(256), 0, stream>>>(Vb, Vt);
  f_attn     <<<dim3(4096),    dim3(256), 0, stream>>>(Qb, Kb, Vt, x, att, xres);
}

// Round 4
// 365.632 us; speedup vs baseline: 1.6799x; 1.6208x over previous
//
#include <hip/hip_runtime.h>
#include <hip/hip_bf16.h>
#include <cstdint>
#include <cstddef>

// Problem constants
#define B_ 8
#define S_ 1024
#define H_ 16
#define E_ 64
#define D_ 1024      // embed dim

typedef unsigned short u16;
typedef short s16x8 __attribute__((ext_vector_type(8)));
typedef float f32x4 __attribute__((ext_vector_type(4)));

// fp32 -> bf16, round-to-nearest-even
__device__ __forceinline__ u16 f2b(float f) {
  union { float f; unsigned u; } v; v.f = f;
  unsigned u = v.u;
  return (u16)((u + 0x7FFFu + ((u >> 16) & 1u)) >> 16);
}

// async global->LDS, 16B per lane. LDS dest is wave-uniform base + lane*16.
__device__ __forceinline__ void gload16(const void* g, void* lds) {
  __builtin_amdgcn_global_load_lds(
      (const __attribute__((address_space(1))) void*)g,
      (__attribute__((address_space(3))) void*)lds, 16, 0, 0);
}

// ---------------- kernel 1: x fp32 -> bf16 ----------------
__global__ void k_cvt_x(const float* __restrict__ x, u16* __restrict__ xb) {
  size_t i = ((size_t)blockIdx.x * 256 + threadIdx.x) * 8;
  float4 a = *(const float4*)(x + i);
  float4 b = *(const float4*)(x + i + 4);
  uint4 o;
  o.x = f2b(a.x) | ((unsigned)f2b(a.y) << 16);
  o.y = f2b(a.z) | ((unsigned)f2b(a.w) << 16);
  o.z = f2b(b.x) | ((unsigned)f2b(b.y) << 16);
  o.w = f2b(b.z) | ((unsigned)f2b(b.w) << 16);
  *(uint4*)(xb + i) = o;
}

// ---------------- kernel 2: build WbT[n][k] bf16 ----------------
__global__ void k_build_wbt(const float* __restrict__ Wq, const float* __restrict__ Wk,
                            const float* __restrict__ Wv, u16* __restrict__ wbt) {
  __shared__ u16 T[64][65];
  int d0 = blockIdx.x * 64;
  int mh = blockIdx.y;
  int mat = mh >> 4, h = mh & 15;
  const float* W = (mat == 0) ? Wq : (mat == 1) ? Wk : Wv;
  int tid = threadIdx.x;
#pragma unroll
  for (int rep = 0; rep < 4; rep++) {
    int dl = rep * 16 + (tid >> 4);
    int e0 = (tid & 15) * 4;
    float4 v = *(const float4*)(W + (size_t)h * (D_ * E_) + (size_t)(d0 + dl) * E_ + e0);
    T[dl][e0] = f2b(v.x); T[dl][e0 + 1] = f2b(v.y);
    T[dl][e0 + 2] = f2b(v.z); T[dl][e0 + 3] = f2b(v.w);
  }
  __syncthreads();
#pragma unroll
  for (int rep = 0; rep < 4; rep++) {
    int el = rep * 16 + (tid >> 4);
    int dl0 = (tid & 15) * 4;
    ushort4 o;
    o.x = T[dl0][el]; o.y = T[dl0 + 1][el]; o.z = T[dl0 + 2][el]; o.w = T[dl0 + 3][el];
    int n = mat * 1024 + h * 64 + el;
    *(ushort4*)(wbt + (size_t)n * D_ + d0 + dl0) = o;
  }
}

// ---------------- kernel 3: QKV GEMM (unchanged, proven) ----------------
__global__ __launch_bounds__(256) void k_qkv(
    const u16* __restrict__ xb, const u16* __restrict__ wbt,
    const float* __restrict__ bq, const float* __restrict__ bk, const float* __restrict__ bv,
    u16* __restrict__ Qb, u16* __restrict__ Kb, u16* __restrict__ Vb) {
  __shared__ u16 As[128 * 64];
  __shared__ u16 Bs[128 * 64];
  int tid = threadIdx.x, l = tid & 63, w = tid >> 6;
  int m0 = blockIdx.y * 128, n0 = blockIdx.x * 128;
  int wm = w >> 1, wn = w & 1;
  int rl = l & 15, kg = l >> 4;
  f32x4 acc[4][4] = {};
  for (int k0 = 0; k0 < D_; k0 += 64) {
#pragma unroll
    for (int i = 0; i < 4; i++) {
      int ci = w * 4 + i;
      int r = ci * 8 + (l >> 3);
      int c = (l & 7) ^ (r & 7);
      gload16(xb  + (size_t)(m0 + r) * D_ + k0 + c * 8, (char*)As + ci * 1024);
      gload16(wbt + (size_t)(n0 + r) * D_ + k0 + c * 8, (char*)Bs + ci * 1024);
    }
    __syncthreads();
#pragma unroll
    for (int kk = 0; kk < 2; kk++) {
      s16x8 af[4], bfr[4];
      int chunk = kk * 4 + kg;
#pragma unroll
      for (int fm = 0; fm < 4; fm++) {
        int r = wm * 64 + fm * 16 + rl;
        af[fm] = *(const s16x8*)(As + r * 64 + ((chunk ^ (r & 7)) * 8));
      }
#pragma unroll
      for (int fn = 0; fn < 4; fn++) {
        int r = wn * 64 + fn * 16 + rl;
        bfr[fn] = *(const s16x8*)(Bs + r * 64 + ((chunk ^ (r & 7)) * 8));
      }
#pragma unroll
      for (int fm = 0; fm < 4; fm++)
#pragma unroll
        for (int fn = 0; fn < 4; fn++)
          acc[fm][fn] = __builtin_amdgcn_mfma_f32_16x16x32_bf16(af[fm], bfr[fn], acc[fm][fn], 0, 0, 0);
    }
    __syncthreads();
  }
#pragma unroll
  for (int fn = 0; fn < 4; fn++) {
    int n = n0 + wn * 64 + fn * 16 + rl;
    int mat = n >> 10, h = (n >> 6) & 15, e = n & 63;
    const float* bias = (mat == 0) ? bq : (mat == 1) ? bk : bv;
    float bval = bias[h * 64 + e];
    u16* dst = (mat == 0) ? Qb : (mat == 1) ? Kb : Vb;
#pragma unroll
    for (int fm = 0; fm < 4; fm++)
#pragma unroll
      for (int j = 0; j < 4; j++) {
        int m = m0 + wm * 64 + fm * 16 + kg * 4 + j;
        int bb = m >> 10, s = m & 1023;
        dst[(size_t)((h * B_ + bb) * S_ + s) * E_ + e] = f2b(acc[fm][fn][j] + bval);
      }
  }
}

// ---------------- kernel 4: Vb[h][b][s][e] -> Vt[h][b][e][s] ----------------
__global__ void k_vt(const u16* __restrict__ Vb, u16* __restrict__ Vt) {
  __shared__ u16 T[64][65];
  int hb = blockIdx.y, s0 = blockIdx.x * 64, tid = threadIdx.x;
  const u16* src = Vb + (size_t)hb * (S_ * E_);
#pragma unroll
  for (int rep = 0; rep < 4; rep++) {
    int sl = rep * 16 + (tid >> 4);
    int e0 = (tid & 15) * 4;
    ushort4 v = *(const ushort4*)(src + (size_t)(s0 + sl) * E_ + e0);
    T[sl][e0] = v.x; T[sl][e0 + 1] = v.y; T[sl][e0 + 2] = v.z; T[sl][e0 + 3] = v.w;
  }
  __syncthreads();
  u16* dst = Vt + (size_t)hb * (S_ * E_);
#pragma unroll
  for (int rep = 0; rep < 4; rep++) {
    int el = rep * 16 + (tid >> 4);
    int sl0 = (tid & 15) * 4;
    ushort4 o;
    o.x = T[sl0][el]; o.y = T[sl0 + 1][el]; o.z = T[sl0 + 2][el]; o.w = T[sl0 + 3][el];
    *(ushort4*)(dst + (size_t)el * S_ + s0 + sl0) = o;
  }
}

// ---------------- kernel 5: fused attention, K/V fully LDS-resident ----------------
// Block = 64 q-rows of one (h,b). 8 waves (512 thr). Phase 1: K panel (1024x64,
// 128KB) resident in LDS -> QK^T loop with ZERO barriers. Phase 2: softmax in
// registers (3 reduce barriers, V load in flight). Phase 3: V^T panel resident
// in same 128KB -> PV with 1 ds-only barrier per chunk. att fp32 stored once at end.
__global__ __launch_bounds__(512, 2) void f_attn(
    const u16* __restrict__ Qb, const u16* __restrict__ Kb, const u16* __restrict__ Vt,
    const float* __restrict__ x, float* __restrict__ att, float* __restrict__ out) {
  __shared__ u16 Qlds[64 * 64];        // 8 KB
  __shared__ u16 KV[1024 * 64];        // 128 KB: K [1024 rows][64], later V^T [64 rows][1024]
  __shared__ u16 Ab[2][64 * 64];       // 16 KB att-bf16 chunk dbuf
  __shared__ float red[3][64][4];      // 3 KB cross-wave reduce

  // XCD-chunked swizzle: 2048 blocks, 256/XCD -> 16 consecutive hb per XCD.
  int p = blockIdx.x;
  int L = (p & 7) * 256 + (p >> 3);
  int hb = L >> 4, mblk = L & 15;
  int m0 = mblk * 64;
  int tid = threadIdx.x, l = tid & 63, w = tid >> 6;  // 8 waves
  int rl = l & 15, kg = l >> 4;
  int rh = w >> 2, cq = w & 3;   // QK: row-half, col-quarter

  const u16* Qp = Qb + (size_t)hb * (S_ * E_) + (size_t)m0 * E_;
  const u16* Kp = Kb + (size_t)hb * (S_ * E_);
  const u16* Vp = Vt + (size_t)hb * (S_ * E_);

  // ---- stage Q (64x64) + FULL K panel (1024x64) ----
  {
    int r = w * 8 + (l >> 3), c = (l & 7) ^ (r & 7);
    gload16(Qp + (size_t)r * E_ + c * 8, (char*)Qlds + w * 1024);
  }
#pragma unroll
  for (int i = 0; i < 16; i++) {
    int ci = w * 16 + i;                       // 0..127, 8 rows each
    int r = ci * 8 + (l >> 3), c = (l & 7) ^ (r & 7);
    gload16(Kp + (size_t)r * E_ + c * 8, (char*)KV + ci * 1024);
  }
  __syncthreads();

  s16x8 af[2][2];
#pragma unroll
  for (int fm = 0; fm < 2; fm++)
#pragma unroll
    for (int kk = 0; kk < 2; kk++) {
      int r = rh * 32 + fm * 16 + rl, ch = kk * 4 + kg;
      af[fm][kk] = *(const s16x8*)((const char*)Qlds + r * 128 + ((ch ^ (r & 7)) * 16));
    }

  f32x4 acc[2][16];
#pragma unroll
  for (int fm = 0; fm < 2; fm++)
#pragma unroll
    for (int ct = 0; ct < 16; ct++)
#pragma unroll
      for (int j = 0; j < 4; j++) acc[fm][ct][j] = 0.f;

  // ---- QK^T: no barriers, K resident. acc[fm][ct][j] = S[rh*32+fm*16+kg*4+j][ct*64+cq*16+rl]
#pragma unroll
  for (int ct = 0; ct < 16; ct++) {
    s16x8 bf[2];
#pragma unroll
    for (int kk = 0; kk < 2; kk++) {
      int r = ct * 64 + cq * 16 + rl, ch = kk * 4 + kg;
      bf[kk] = *(const s16x8*)((const char*)KV + r * 128 + ((ch ^ (r & 7)) * 16));
    }
#pragma unroll
    for (int fm = 0; fm < 2; fm++)
#pragma unroll
      for (int kk = 0; kk < 2; kk++)
        acc[fm][ct] = __builtin_amdgcn_mfma_f32_16x16x32_bf16(af[fm][kk], bf[kk], acc[fm][ct], 0, 0, 0);
  }
  __syncthreads();   // all K reads done -> safe to overwrite KV with V

  // ---- issue FULL V^T panel load (64 rows e x 1024 t, row stride 2048B, swizzled) ----
#pragma unroll
  for (int i = 0; i < 16; i++) {
    int ci = w * 16 + i;                 // 0..127: e = ci>>1, half hf = ci&1
    int e = ci >> 1, hf = ci & 1;
    // lane l writes 16B slot s = hf*64 + l; slot s holds logical chunk c:
    // s = (c & ~7) | ((c&7) ^ (e&7))  =>  c = (s & ~7) | ((s&7) ^ (e&7))
    // per-lane source pre-swizzle with s = hf*64 + l:
    int c = ((hf * 64 + l) & ~7) | (((l) & 7) ^ (e & 7));
    gload16(Vp + (size_t)e * S_ + c * 8, (char*)KV + e * 2048 + hf * 1024);
  }

  // ---- softmax over rows (scale 1/32 folded into exp); V load in flight ----
  float mx[2][4], Z[2][4];
#pragma unroll
  for (int fm = 0; fm < 2; fm++)
#pragma unroll
    for (int j = 0; j < 4; j++) {
      float m = acc[fm][0][j];
#pragma unroll
      for (int ct = 1; ct < 16; ct++) m = fmaxf(m, acc[fm][ct][j]);
#pragma unroll
      for (int off = 8; off >= 1; off >>= 1) m = fmaxf(m, __shfl_xor(m, off));
      mx[fm][j] = m;
    }
  if (rl == 0) {
#pragma unroll
    for (int fm = 0; fm < 2; fm++)
#pragma unroll
      for (int j = 0; j < 4; j++) red[0][rh * 32 + fm * 16 + kg * 4 + j][cq] = mx[fm][j];
  }
  __syncthreads();
#pragma unroll
  for (int fm = 0; fm < 2; fm++)
#pragma unroll
    for (int j = 0; j < 4; j++) {
      f32x4 r4 = *(const f32x4*)&red[0][rh * 32 + fm * 16 + kg * 4 + j][0];
      mx[fm][j] = fmaxf(fmaxf(r4[0], r4[1]), fmaxf(r4[2], r4[3]));
    }
#pragma unroll
  for (int fm = 0; fm < 2; fm++)
#pragma unroll
    for (int j = 0; j < 4; j++) {
      float s = 0.f;
#pragma unroll
      for (int ct = 0; ct < 16; ct++) {
        float e = __expf((acc[fm][ct][j] - mx[fm][j]) * 0.03125f);
        acc[fm][ct][j] = e;
        s += e;
      }
#pragma unroll
      for (int off = 8; off >= 1; off >>= 1) s += __shfl_xor(s, off);
      Z[fm][j] = s;
    }
  if (rl == 0) {
#pragma unroll
    for (int fm = 0; fm < 2; fm++)
#pragma unroll
      for (int j = 0; j < 4; j++) red[1][rh * 32 + fm * 16 + kg * 4 + j][cq] = Z[fm][j];
  }
  __syncthreads();
#pragma unroll
  for (int fm = 0; fm < 2; fm++)
#pragma unroll
    for (int j = 0; j < 4; j++) {
      f32x4 r4 = *(const f32x4*)&red[1][rh * 32 + fm * 16 + kg * 4 + j][0];
      Z[fm][j] = r4[0] + r4[1] + r4[2] + r4[3];
    }
  // threshold: keep e >= 0.001*Z (<=> p >= 0.001), re-sum survivors
#pragma unroll
  for (int fm = 0; fm < 2; fm++)
#pragma unroll
    for (int j = 0; j < 4; j++) {
      float thr = 0.001f * Z[fm][j];
      float s = 0.f;
#pragma unroll
      for (int ct = 0; ct < 16; ct++) {
        float e = acc[fm][ct][j];
        e = (e >= thr) ? e : 0.f;
        acc[fm][ct][j] = e;
        s += e;
      }
#pragma unroll
      for (int off = 8; off >= 1; off >>= 1) s += __shfl_xor(s, off);
      red[2][0][0] = red[2][0][0];  // no-op to keep structure
      Z[fm][j] = (Z[fm][j] == 0.f) ? 0.f : Z[fm][j];  // keep Z live
      mx[fm][j] = s;  // reuse mx as Z2 partial
    }
  if (rl == 0) {
#pragma unroll
    for (int fm = 0; fm < 2; fm++)
#pragma unroll
      for (int j = 0; j < 4; j++) red[2][rh * 32 + fm * 16 + kg * 4 + j][cq] = mx[fm][j];
  }
  __syncthreads();
#pragma unroll
  for (int fm = 0; fm < 2; fm++)
#pragma unroll
    for (int j = 0; j < 4; j++) {
      f32x4 r4 = *(const f32x4*)&red[2][rh * 32 + fm * 16 + kg * 4 + j][0];
      float z2 = r4[0] + r4[1] + r4[2] + r4[3];
      float inv = 1.f / (z2 + 1e-12f * Z[fm][j]);  // == p/(sum_kept_p + 1e-12)
#pragma unroll
      for (int ct = 0; ct < 16; ct++) acc[fm][ct][j] *= inv;
    }

  // ---- PV: V resident in KV; per chunk: write Ab (bf16), 1 barrier, 4 MFMA ----
  int mh2 = w >> 1, nh2 = w & 1;   // PV wave: rows mh2*16.., cols nh2*32 + fn*16
  f32x4 acc2[2];
#pragma unroll
  for (int fn = 0; fn < 2; fn++)
#pragma unroll
    for (int j = 0; j < 4; j++) acc2[fn][j] = 0.f;

#pragma unroll
  for (int ct = 0; ct < 16; ct++) {
#pragma unroll
    for (int fm = 0; fm < 2; fm++)
#pragma unroll
      for (int j = 0; j < 4; j++) {
        int m = rh * 32 + fm * 16 + kg * 4 + j;
        int tl = cq * 16 + rl;
        int chw = tl >> 3;
        *(u16*)((char*)Ab[ct & 1] + m * 128 + ((chw ^ (m & 7)) * 16) + (tl & 7) * 2)
            = f2b(acc[fm][ct][j]);
      }
    __syncthreads();   // ds-only drain (no vmcnt pending except V load on ct=0, already drained)
    s16x8 a2[2], b2[2][2];
#pragma unroll
    for (int kk = 0; kk < 2; kk++) {
      int ch = kk * 4 + kg;
      int rA = mh2 * 16 + rl;
      a2[kk] = *(const s16x8*)((const char*)Ab[ct & 1] + rA * 128 + ((ch ^ (rA & 7)) * 16));
#pragma unroll
      for (int fn = 0; fn < 2; fn++) {
        int e = nh2 * 32 + fn * 16 + rl;
        b2[fn][kk] = *(const s16x8*)((const char*)KV + e * 2048 + ct * 128 + ((ch ^ (e & 7)) * 16));
      }
    }
#pragma unroll
    for (int fn = 0; fn < 2; fn++)
#pragma unroll
      for (int kk = 0; kk < 2; kk++)
        acc2[fn] = __builtin_amdgcn_mfma_f32_16x16x32_bf16(a2[kk], b2[fn][kk], acc2[fn], 0, 0, 0);
  }

  // ---- att fp32 store (once, fire-and-forget) ----
  float* attp = att + ((size_t)hb << 20) + ((size_t)m0 << 10);
#pragma unroll
  for (int fm = 0; fm < 2; fm++)
#pragma unroll
    for (int j = 0; j < 4; j++) {
      int m = rh * 32 + fm * 16 + kg * 4 + j;
#pragma unroll
      for (int ct = 0; ct < 16; ct++)
        attp[((size_t)m << 10) + ct * 64 + cq * 16 + rl] = acc[fm][ct][j];
    }

  // ---- epilogue: out = x + latent ----
  int h = hb >> 3, bb = hb & 7;
#pragma unroll
  for (int fn = 0; fn < 2; fn++)
#pragma unroll
    for (int j = 0; j < 4; j++) {
      int m = m0 + mh2 * 16 + kg * 4 + j;
      int e = h * 64 + nh2 * 32 + fn * 16 + rl;
      size_t idx = (((size_t)bb * S_ + m) << 10) + e;
      out[idx] = x[idx] + acc2[fn][j];
    }
}

extern "C" void kernel_launch(void* const* d_in, const int* in_sizes, int n_in,
                              void* d_out, int out_size, void* d_ws, size_t ws_size,
                              hipStream_t stream) {
  const float* x  = (const float*)d_in[0];
  const float* Wq = (const float*)d_in[1];
  const float* bq = (const float*)d_in[2];
  const float* Wk = (const float*)d_in[3];
  const float* bk = (const float*)d_in[4];
  const float* Wv = (const float*)d_in[5];
  const float* bv = (const float*)d_in[6];
  float* xres = (float*)d_out;
  float* att  = xres + (size_t)B_ * S_ * D_;

  char* ws = (char*)d_ws;
  u16* xb  = (u16*)(ws);                  // 16 MB
  u16* wbt = (u16*)(ws + 16777216);       //  6 MB
  u16* Qb  = (u16*)(ws + 23068672);       // 16 MB
  u16* Kb  = (u16*)(ws + 39845888);       // 16 MB
  u16* Vb  = (u16*)(ws + 56623104);       // 16 MB
  u16* Vt  = (u16*)(ws);                  // aliases xb (dead after k_qkv)

  k_cvt_x    <<<dim3(4096),    dim3(256), 0, stream>>>(x, xb);
  k_build_wbt<<<dim3(16, 48),  dim3(256), 0, stream>>>(Wq, Wk, Wv, wbt);
  k_qkv      <<<dim3(24, 64),  dim3(256), 0, stream>>>(xb, wbt, bq, bk, bv, Qb, Kb, Vb);
  k_vt       <<<dim3(16, 128), dim3(256), 0, stream>>>(Vb, Vt);
  f_attn     <<<dim3(2048),    dim3(512), 0, stream>>>(Qb, Kb, Vt, x, att, xres);
}

// Round 5
// 299.307 us; speedup vs baseline: 2.0522x; 1.2216x over previous
//
#include <hip/hip_runtime.h>
#include <hip/hip_bf16.h>
#include <cstdint>
#include <cstddef>

// Problem constants
#define B_ 8
#define S_ 1024
#define H_ 16
#define E_ 64
#define D_ 1024      // embed dim

typedef unsigned short u16;
typedef short s16x8 __attribute__((ext_vector_type(8)));
typedef float f32x4 __attribute__((ext_vector_type(4)));

// fp32 -> bf16, round-to-nearest-even
__device__ __forceinline__ u16 f2b(float f) {
  union { float f; unsigned u; } v; v.f = f;
  unsigned u = v.u;
  return (u16)((u + 0x7FFFu + ((u >> 16) & 1u)) >> 16);
}

// async global->LDS, 16B per lane. LDS dest is wave-uniform base + lane*16.
__device__ __forceinline__ void gload16(const void* g, void* lds) {
  __builtin_amdgcn_global_load_lds(
      (const __attribute__((address_space(1))) void*)g,
      (__attribute__((address_space(3))) void*)lds, 16, 0, 0);
}

// LDS-only barrier: drain own DS ops, raw s_barrier, fenced against compiler
// motion (rule #18: sched_barrier after inline-asm waitcnt; memory clobbers
// block IR-level reordering of LDS accesses across the barrier).
#define BARL() do {                                          \
  asm volatile("s_waitcnt lgkmcnt(0)" ::: "memory");         \
  __builtin_amdgcn_sched_barrier(0);                         \
  __builtin_amdgcn_s_barrier();                              \
  __builtin_amdgcn_sched_barrier(0);                         \
  asm volatile("" ::: "memory");                             \
} while (0)

// ---------------- kernel 1: merged x->bf16 cvt + WbT build ----------------
__global__ void k_prep(const float* __restrict__ x, u16* __restrict__ xb,
                       const float* __restrict__ Wq, const float* __restrict__ Wk,
                       const float* __restrict__ Wv, u16* __restrict__ wbt) {
  if (blockIdx.x < 4096) {
    size_t i = ((size_t)blockIdx.x * 256 + threadIdx.x) * 8;
    float4 a = *(const float4*)(x + i);
    float4 b = *(const float4*)(x + i + 4);
    uint4 o;
    o.x = f2b(a.x) | ((unsigned)f2b(a.y) << 16);
    o.y = f2b(a.z) | ((unsigned)f2b(a.w) << 16);
    o.z = f2b(b.x) | ((unsigned)f2b(b.y) << 16);
    o.w = f2b(b.z) | ((unsigned)f2b(b.w) << 16);
    *(uint4*)(xb + i) = o;
    return;
  }
  __shared__ u16 T[64][65];
  int bid = blockIdx.x - 4096;           // 0..767
  int d0 = (bid & 15) * 64;              // 16 d-tiles
  int mh = bid >> 4;                     // 48 = 3 mats * 16 heads
  int mat = mh >> 4, h = mh & 15;
  const float* W = (mat == 0) ? Wq : (mat == 1) ? Wk : Wv;
  int tid = threadIdx.x;
#pragma unroll
  for (int rep = 0; rep < 4; rep++) {
    int dl = rep * 16 + (tid >> 4);
    int e0 = (tid & 15) * 4;
    float4 v = *(const float4*)(W + (size_t)h * (D_ * E_) + (size_t)(d0 + dl) * E_ + e0);
    T[dl][e0] = f2b(v.x); T[dl][e0 + 1] = f2b(v.y);
    T[dl][e0 + 2] = f2b(v.z); T[dl][e0 + 3] = f2b(v.w);
  }
  __syncthreads();
#pragma unroll
  for (int rep = 0; rep < 4; rep++) {
    int el = rep * 16 + (tid >> 4);
    int dl0 = (tid & 15) * 4;
    ushort4 o;
    o.x = T[dl0][el]; o.y = T[dl0 + 1][el]; o.z = T[dl0 + 2][el]; o.w = T[dl0 + 3][el];
    int n = mat * 1024 + h * 64 + el;
    *(ushort4*)(wbt + (size_t)n * D_ + d0 + dl0) = o;
  }
}

// ---------------- kernel 3: QKV GEMM, XCD-chunked ----------------
__global__ __launch_bounds__(256) void k_qkv(
    const u16* __restrict__ xb, const u16* __restrict__ wbt,
    const float* __restrict__ bq, const float* __restrict__ bk, const float* __restrict__ bv,
    u16* __restrict__ Qb, u16* __restrict__ Kb, u16* __restrict__ Vb) {
  __shared__ u16 As[128 * 64];
  __shared__ u16 Bs[128 * 64];
  int tid = threadIdx.x, l = tid & 63, w = tid >> 6;
  // 1536 blocks; bid&7 = XCD. Each XCD owns 8 consecutive m-blocks x 24 n-blocks:
  // A slice (2MB) L2-resident, B panel (6MB) streamed once then L3-hit.
  int bid = blockIdx.x;
  int xcd = bid & 7, i = bid >> 3;       // i in 0..191
  int m0 = (xcd * 8 + i / 24) * 128;
  int n0 = (i % 24) * 128;
  int wm = w >> 1, wn = w & 1;
  int rl = l & 15, kg = l >> 4;
  f32x4 acc[4][4] = {};
  for (int k0 = 0; k0 < D_; k0 += 64) {
#pragma unroll
    for (int i2 = 0; i2 < 4; i2++) {
      int ci = w * 4 + i2;
      int r = ci * 8 + (l >> 3);
      int c = (l & 7) ^ (r & 7);
      gload16(xb  + (size_t)(m0 + r) * D_ + k0 + c * 8, (char*)As + ci * 1024);
      gload16(wbt + (size_t)(n0 + r) * D_ + k0 + c * 8, (char*)Bs + ci * 1024);
    }
    __syncthreads();
#pragma unroll
    for (int kk = 0; kk < 2; kk++) {
      s16x8 af[4], bfr[4];
      int chunk = kk * 4 + kg;
#pragma unroll
      for (int fm = 0; fm < 4; fm++) {
        int r = wm * 64 + fm * 16 + rl;
        af[fm] = *(const s16x8*)(As + r * 64 + ((chunk ^ (r & 7)) * 8));
      }
#pragma unroll
      for (int fn = 0; fn < 4; fn++) {
        int r = wn * 64 + fn * 16 + rl;
        bfr[fn] = *(const s16x8*)(Bs + r * 64 + ((chunk ^ (r & 7)) * 8));
      }
#pragma unroll
      for (int fm = 0; fm < 4; fm++)
#pragma unroll
        for (int fn = 0; fn < 4; fn++)
          acc[fm][fn] = __builtin_amdgcn_mfma_f32_16x16x32_bf16(af[fm], bfr[fn], acc[fm][fn], 0, 0, 0);
    }
    __syncthreads();
  }
#pragma unroll
  for (int fn = 0; fn < 4; fn++) {
    int n = n0 + wn * 64 + fn * 16 + rl;
    int mat = n >> 10, h = (n >> 6) & 15, e = n & 63;
    const float* bias = (mat == 0) ? bq : (mat == 1) ? bk : bv;
    float bval = bias[h * 64 + e];
    u16* dst = (mat == 0) ? Qb : (mat == 1) ? Kb : Vb;
#pragma unroll
    for (int fm = 0; fm < 4; fm++)
#pragma unroll
      for (int j = 0; j < 4; j++) {
        int m = m0 + wm * 64 + fm * 16 + kg * 4 + j;
        int bb = m >> 10, s = m & 1023;
        dst[(size_t)((h * B_ + bb) * S_ + s) * E_ + e] = f2b(acc[fm][fn][j] + bval);
      }
  }
}

// ---------------- kernel 4: Vb[h][b][s][e] -> Vt[h][b][e][s] ----------------
__global__ void k_vt(const u16* __restrict__ Vb, u16* __restrict__ Vt) {
  __shared__ u16 T[64][65];
  int hb = blockIdx.y, s0 = blockIdx.x * 64, tid = threadIdx.x;
  const u16* src = Vb + (size_t)hb * (S_ * E_);
#pragma unroll
  for (int rep = 0; rep < 4; rep++) {
    int sl = rep * 16 + (tid >> 4);
    int e0 = (tid & 15) * 4;
    ushort4 v = *(const ushort4*)(src + (size_t)(s0 + sl) * E_ + e0);
    T[sl][e0] = v.x; T[sl][e0 + 1] = v.y; T[sl][e0 + 2] = v.z; T[sl][e0 + 3] = v.w;
  }
  __syncthreads();
  u16* dst = Vt + (size_t)hb * (S_ * E_);
#pragma unroll
  for (int rep = 0; rep < 4; rep++) {
    int el = rep * 16 + (tid >> 4);
    int sl0 = (tid & 15) * 4;
    ushort4 o;
    o.x = T[sl0][el]; o.y = T[sl0 + 1][el]; o.z = T[sl0 + 2][el]; o.w = T[sl0 + 3][el];
    *(ushort4*)(dst + (size_t)el * S_ + s0 + sl0) = o;
  }
}

// ---------------- kernel 5: fused attention, K/V LDS-resident, lgkm-only barriers ----
__global__ __launch_bounds__(512, 2) void f_attn(
    const u16* __restrict__ Qb, const u16* __restrict__ Kb, const u16* __restrict__ Vt,
    const float* __restrict__ x, float* __restrict__ att, float* __restrict__ out) {
  __shared__ u16 Qlds[64 * 64];        // 8 KB
  __shared__ u16 KV[1024 * 64];        // 128 KB: K panel, later V^T panel
  __shared__ u16 Ab[2][64 * 64];       // 16 KB att-bf16 chunk dbuf
  __shared__ float red[3][64][4];      // 3 KB cross-wave reduce

  int p = blockIdx.x;
  int L = (p & 7) * 256 + (p >> 3);    // XCD-chunked: 16 consecutive hb per XCD
  int hb = L >> 4, mblk = L & 15;
  int m0 = mblk * 64;
  int tid = threadIdx.x, l = tid & 63, w = tid >> 6;  // 8 waves
  int rl = l & 15, kg = l >> 4;
  int rh = w >> 2, cq = w & 3;   // QK: row-half, col-quarter

  const u16* Qp = Qb + (size_t)hb * (S_ * E_) + (size_t)m0 * E_;
  const u16* Kp = Kb + (size_t)hb * (S_ * E_);
  const u16* Vp = Vt + (size_t)hb * (S_ * E_);

  // ---- stage Q (64x64) + FULL K panel (1024x64) ----
  {
    int r = w * 8 + (l >> 3), c = (l & 7) ^ (r & 7);
    gload16(Qp + (size_t)r * E_ + c * 8, (char*)Qlds + w * 1024);
  }
#pragma unroll
  for (int i = 0; i < 16; i++) {
    int ci = w * 16 + i;
    int r = ci * 8 + (l >> 3), c = (l & 7) ^ (r & 7);
    gload16(Kp + (size_t)r * E_ + c * 8, (char*)KV + ci * 1024);
  }
  __syncthreads();   // full drain required: K,Q must be in LDS

  s16x8 af[2][2];
#pragma unroll
  for (int fm = 0; fm < 2; fm++)
#pragma unroll
    for (int kk = 0; kk < 2; kk++) {
      int r = rh * 32 + fm * 16 + rl, ch = kk * 4 + kg;
      af[fm][kk] = *(const s16x8*)((const char*)Qlds + r * 128 + ((ch ^ (r & 7)) * 16));
    }

  f32x4 acc[2][16];
#pragma unroll
  for (int fm = 0; fm < 2; fm++)
#pragma unroll
    for (int ct = 0; ct < 16; ct++)
#pragma unroll
      for (int j = 0; j < 4; j++) acc[fm][ct][j] = 0.f;

  // ---- QK^T: no barriers, K resident ----
#pragma unroll
  for (int ct = 0; ct < 16; ct++) {
    s16x8 bf[2];
#pragma unroll
    for (int kk = 0; kk < 2; kk++) {
      int r = ct * 64 + cq * 16 + rl, ch = kk * 4 + kg;
      bf[kk] = *(const s16x8*)((const char*)KV + r * 128 + ((ch ^ (r & 7)) * 16));
    }
#pragma unroll
    for (int fm = 0; fm < 2; fm++)
#pragma unroll
      for (int kk = 0; kk < 2; kk++)
        acc[fm][ct] = __builtin_amdgcn_mfma_f32_16x16x32_bf16(af[fm][kk], bf[kk], acc[fm][ct], 0, 0, 0);
  }
  __syncthreads();   // all K reads done -> safe to overwrite KV with V

  // ---- issue FULL V^T panel load (stays in flight through softmax) ----
#pragma unroll
  for (int i = 0; i < 16; i++) {
    int ci = w * 16 + i;
    int e = ci >> 1, hf = ci & 1;
    int c = ((hf * 64 + l) & ~7) | ((l & 7) ^ (e & 7));
    gload16(Vp + (size_t)e * S_ + c * 8, (char*)KV + e * 2048 + hf * 1024);
  }

  // ---- softmax (scale 1/32 folded into exp); lgkm-only barriers keep V in flight ----
  float mx[2][4], Z[2][4], Z2[2][4];
#pragma unroll
  for (int fm = 0; fm < 2; fm++)
#pragma unroll
    for (int j = 0; j < 4; j++) {
      float m = acc[fm][0][j];
#pragma unroll
      for (int ct = 1; ct < 16; ct++) m = fmaxf(m, acc[fm][ct][j]);
#pragma unroll
      for (int off = 8; off >= 1; off >>= 1) m = fmaxf(m, __shfl_xor(m, off));
      mx[fm][j] = m;
    }
  if (rl == 0) {
#pragma unroll
    for (int fm = 0; fm < 2; fm++)
#pragma unroll
      for (int j = 0; j < 4; j++) red[0][rh * 32 + fm * 16 + kg * 4 + j][cq] = mx[fm][j];
  }
  BARL();
#pragma unroll
  for (int fm = 0; fm < 2; fm++)
#pragma unroll
    for (int j = 0; j < 4; j++) {
      f32x4 r4 = *(const f32x4*)&red[0][rh * 32 + fm * 16 + kg * 4 + j][0];
      mx[fm][j] = fmaxf(fmaxf(r4[0], r4[1]), fmaxf(r4[2], r4[3]));
    }
#pragma unroll
  for (int fm = 0; fm < 2; fm++)
#pragma unroll
    for (int j = 0; j < 4; j++) {
      float s = 0.f;
#pragma unroll
      for (int ct = 0; ct < 16; ct++) {
        float e = __expf((acc[fm][ct][j] - mx[fm][j]) * 0.03125f);
        acc[fm][ct][j] = e;
        s += e;
      }
#pragma unroll
      for (int off = 8; off >= 1; off >>= 1) s += __shfl_xor(s, off);
      Z[fm][j] = s;
    }
  if (rl == 0) {
#pragma unroll
    for (int fm = 0; fm < 2; fm++)
#pragma unroll
      for (int j = 0; j < 4; j++) red[1][rh * 32 + fm * 16 + kg * 4 + j][cq] = Z[fm][j];
  }
  BARL();
#pragma unroll
  for (int fm = 0; fm < 2; fm++)
#pragma unroll
    for (int j = 0; j < 4; j++) {
      f32x4 r4 = *(const f32x4*)&red[1][rh * 32 + fm * 16 + kg * 4 + j][0];
      Z[fm][j] = r4[0] + r4[1] + r4[2] + r4[3];
    }
  // threshold: keep e >= 0.001*Z (<=> p >= 0.001), re-sum survivors
#pragma unroll
  for (int fm = 0; fm < 2; fm++)
#pragma unroll
    for (int j = 0; j < 4; j++) {
      float thr = 0.001f * Z[fm][j];
      float s = 0.f;
#pragma unroll
      for (int ct = 0; ct < 16; ct++) {
        float e = acc[fm][ct][j];
        e = (e >= thr) ? e : 0.f;
        acc[fm][ct][j] = e;
        s += e;
      }
#pragma unroll
      for (int off = 8; off >= 1; off >>= 1) s += __shfl_xor(s, off);
      Z2[fm][j] = s;
    }
  if (rl == 0) {
#pragma unroll
    for (int fm = 0; fm < 2; fm++)
#pragma unroll
      for (int j = 0; j < 4; j++) red[2][rh * 32 + fm * 16 + kg * 4 + j][cq] = Z2[fm][j];
  }
  BARL();
#pragma unroll
  for (int fm = 0; fm < 2; fm++)
#pragma unroll
    for (int j = 0; j < 4; j++) {
      f32x4 r4 = *(const f32x4*)&red[2][rh * 32 + fm * 16 + kg * 4 + j][0];
      float z2 = r4[0] + r4[1] + r4[2] + r4[3];
      float inv = 1.f / (z2 + 1e-12f * Z[fm][j]);  // == p/(sum_kept_p + 1e-12)
#pragma unroll
      for (int ct = 0; ct < 16; ct++) acc[fm][ct][j] *= inv;
    }

  // ---- retire own V loads (all waves ordered by first PV barrier) ----
  asm volatile("s_waitcnt vmcnt(0)" ::: "memory");
  __builtin_amdgcn_sched_barrier(0);

  // ---- att fp32 stores: issued now, fly under the whole PV loop, never waited ----
  float* attp = att + ((size_t)hb << 20) + ((size_t)m0 << 10);
#pragma unroll
  for (int fm = 0; fm < 2; fm++)
#pragma unroll
    for (int j = 0; j < 4; j++) {
      int m = rh * 32 + fm * 16 + kg * 4 + j;
#pragma unroll
      for (int ct = 0; ct < 16; ct++)
        attp[((size_t)m << 10) + ct * 64 + cq * 16 + rl] = acc[fm][ct][j];
    }

  // ---- PV: per chunk: Ab bf16 write, lgkm barrier, 4 MFMA ----
  int mh2 = w >> 1, nh2 = w & 1;
  f32x4 acc2[2];
#pragma unroll
  for (int fn = 0; fn < 2; fn++)
#pragma unroll
    for (int j = 0; j < 4; j++) acc2[fn][j] = 0.f;

#pragma unroll
  for (int ct = 0; ct < 16; ct++) {
#pragma unroll
    for (int fm = 0; fm < 2; fm++)
#pragma unroll
      for (int j = 0; j < 4; j++) {
        int m = rh * 32 + fm * 16 + kg * 4 + j;
        int tl = cq * 16 + rl;
        int chw = tl >> 3;
        *(u16*)((char*)Ab[ct & 1] + m * 128 + ((chw ^ (m & 7)) * 16) + (tl & 7) * 2)
            = f2b(acc[fm][ct][j]);
      }
    BARL();
    s16x8 a2[2], b2[2][2];
#pragma unroll
    for (int kk = 0; kk < 2; kk++) {
      int ch = kk * 4 + kg;
      int rA = mh2 * 16 + rl;
      a2[kk] = *(const s16x8*)((const char*)Ab[ct & 1] + rA * 128 + ((ch ^ (rA & 7)) * 16));
#pragma unroll
      for (int fn = 0; fn < 2; fn++) {
        int e = nh2 * 32 + fn * 16 + rl;
        b2[fn][kk] = *(const s16x8*)((const char*)KV + e * 2048 + ct * 128 + ((ch ^ (e & 7)) * 16));
      }
    }
#pragma unroll
    for (int fn = 0; fn < 2; fn++)
#pragma unroll
      for (int kk = 0; kk < 2; kk++)
        acc2[fn] = __builtin_amdgcn_mfma_f32_16x16x32_bf16(a2[kk], b2[fn][kk], acc2[fn], 0, 0, 0);
  }

  // ---- epilogue: out = x + latent ----
  int h = hb >> 3, bb = hb & 7;
#pragma unroll
  for (int fn = 0; fn < 2; fn++)
#pragma unroll
    for (int j = 0; j < 4; j++) {
      int m = m0 + mh2 * 16 + kg * 4 + j;
      int e = h * 64 + nh2 * 32 + fn * 16 + rl;
      size_t idx = (((size_t)bb * S_ + m) << 10) + e;
      out[idx] = x[idx] + acc2[fn][j];
    }
}

extern "C" void kernel_launch(void* const* d_in, const int* in_sizes, int n_in,
                              void* d_out, int out_size, void* d_ws, size_t ws_size,
                              hipStream_t stream) {
  const float* x  = (const float*)d_in[0];
  const float* Wq = (const float*)d_in[1];
  const float* bq = (const float*)d_in[2];
  const float* Wk = (const float*)d_in[3];
  const float* bk = (const float*)d_in[4];
  const float* Wv = (const float*)d_in[5];
  const float* bv = (const float*)d_in[6];
  float* xres = (float*)d_out;
  float* att  = xres + (size_t)B_ * S_ * D_;

  char* ws = (char*)d_ws;
  u16* xb  = (u16*)(ws);                  // 16 MB
  u16* wbt = (u16*)(ws + 16777216);       //  6 MB
  u16* Qb  = (u16*)(ws + 23068672);       // 16 MB
  u16* Kb  = (u16*)(ws + 39845888);       // 16 MB
  u16* Vb  = (u16*)(ws + 56623104);       // 16 MB
  u16* Vt  = (u16*)(ws);                  // aliases xb (dead after k_qkv)

  k_prep  <<<dim3(4864),    dim3(256), 0, stream>>>(x, xb, Wq, Wk, Wv, wbt);
  k_qkv   <<<dim3(1536),    dim3(256), 0, stream>>>(xb, wbt, bq, bk, bv, Qb, Kb, Vb);
  k_vt    <<<dim3(16, 128), dim3(256), 0, stream>>>(Vb, Vt);
  f_attn  <<<dim3(2048),    dim3(512), 0, stream>>>(Qb, Kb, Vt, x, att, xres);
}

// Round 6
// 296.731 us; speedup vs baseline: 2.0700x; 1.0087x over previous
//
#include <hip/hip_runtime.h>
#include <hip/hip_bf16.h>
#include <cstdint>
#include <cstddef>

// Problem constants
#define B_ 8
#define S_ 1024
#define H_ 16
#define E_ 64
#define D_ 1024      // embed dim

typedef unsigned short u16;
typedef short s16x8 __attribute__((ext_vector_type(8)));
typedef float f32x4 __attribute__((ext_vector_type(4)));

// fp32 -> bf16, round-to-nearest-even
__device__ __forceinline__ u16 f2b(float f) {
  union { float f; unsigned u; } v; v.f = f;
  unsigned u = v.u;
  return (u16)((u + 0x7FFFu + ((u >> 16) & 1u)) >> 16);
}

// async global->LDS, 16B per lane. LDS dest is wave-uniform base + lane*16.
__device__ __forceinline__ void gload16(const void* g, void* lds) {
  __builtin_amdgcn_global_load_lds(
      (const __attribute__((address_space(1))) void*)g,
      (__attribute__((address_space(3))) void*)lds, 16, 0, 0);
}

// LDS-only barrier: drain own DS ops, raw s_barrier, fenced against compiler
// motion (rule #18: sched_barrier after inline-asm waitcnt).
#define BARL() do {                                          \
  asm volatile("s_waitcnt lgkmcnt(0)" ::: "memory");         \
  __builtin_amdgcn_sched_barrier(0);                         \
  __builtin_amdgcn_s_barrier();                              \
  __builtin_amdgcn_sched_barrier(0);                         \
  asm volatile("" ::: "memory");                             \
} while (0)

// ---------------- kernel 1: merged x->bf16 cvt + WbT build ----------------
__global__ void k_prep(const float* __restrict__ x, u16* __restrict__ xb,
                       const float* __restrict__ Wq, const float* __restrict__ Wk,
                       const float* __restrict__ Wv, u16* __restrict__ wbt) {
  if (blockIdx.x < 4096) {
    size_t i = ((size_t)blockIdx.x * 256 + threadIdx.x) * 8;
    float4 a = *(const float4*)(x + i);
    float4 b = *(const float4*)(x + i + 4);
    uint4 o;
    o.x = f2b(a.x) | ((unsigned)f2b(a.y) << 16);
    o.y = f2b(a.z) | ((unsigned)f2b(a.w) << 16);
    o.z = f2b(b.x) | ((unsigned)f2b(b.y) << 16);
    o.w = f2b(b.z) | ((unsigned)f2b(b.w) << 16);
    *(uint4*)(xb + i) = o;
    return;
  }
  __shared__ u16 T[64][65];
  int bid = blockIdx.x - 4096;           // 0..767
  int d0 = (bid & 15) * 64;              // 16 d-tiles
  int mh = bid >> 4;                     // 48 = 3 mats * 16 heads
  int mat = mh >> 4, h = mh & 15;
  const float* W = (mat == 0) ? Wq : (mat == 1) ? Wk : Wv;
  int tid = threadIdx.x;
#pragma unroll
  for (int rep = 0; rep < 4; rep++) {
    int dl = rep * 16 + (tid >> 4);
    int e0 = (tid & 15) * 4;
    float4 v = *(const float4*)(W + (size_t)h * (D_ * E_) + (size_t)(d0 + dl) * E_ + e0);
    T[dl][e0] = f2b(v.x); T[dl][e0 + 1] = f2b(v.y);
    T[dl][e0 + 2] = f2b(v.z); T[dl][e0 + 3] = f2b(v.w);
  }
  __syncthreads();
#pragma unroll
  for (int rep = 0; rep < 4; rep++) {
    int el = rep * 16 + (tid >> 4);
    int dl0 = (tid & 15) * 4;
    ushort4 o;
    o.x = T[dl0][el]; o.y = T[dl0 + 1][el]; o.z = T[dl0 + 2][el]; o.w = T[dl0 + 3][el];
    int n = mat * 1024 + h * 64 + el;
    *(ushort4*)(wbt + (size_t)n * D_ + d0 + dl0) = o;
  }
}

// ---------------- kernel 2: QKV GEMM, XCD-chunked, V written pre-transposed ----
__global__ __launch_bounds__(256) void k_qkv(
    const u16* __restrict__ xb, const u16* __restrict__ wbt,
    const float* __restrict__ bq, const float* __restrict__ bk, const float* __restrict__ bv,
    u16* __restrict__ Qb, u16* __restrict__ Kb, u16* __restrict__ Vt) {
  __shared__ u16 As[128 * 64];
  __shared__ u16 Bs[128 * 64];
  int tid = threadIdx.x, l = tid & 63, w = tid >> 6;
  int bid = blockIdx.x;
  int xcd = bid & 7, i = bid >> 3;       // i in 0..191
  int m0 = (xcd * 8 + i / 24) * 128;
  int n0 = (i % 24) * 128;
  int wm = w >> 1, wn = w & 1;
  int rl = l & 15, kg = l >> 4;
  f32x4 acc[4][4] = {};
  for (int k0 = 0; k0 < D_; k0 += 64) {
#pragma unroll
    for (int i2 = 0; i2 < 4; i2++) {
      int ci = w * 4 + i2;
      int r = ci * 8 + (l >> 3);
      int c = (l & 7) ^ (r & 7);
      gload16(xb  + (size_t)(m0 + r) * D_ + k0 + c * 8, (char*)As + ci * 1024);
      gload16(wbt + (size_t)(n0 + r) * D_ + k0 + c * 8, (char*)Bs + ci * 1024);
    }
    __syncthreads();
#pragma unroll
    for (int kk = 0; kk < 2; kk++) {
      s16x8 af[4], bfr[4];
      int chunk = kk * 4 + kg;
#pragma unroll
      for (int fm = 0; fm < 4; fm++) {
        int r = wm * 64 + fm * 16 + rl;
        af[fm] = *(const s16x8*)(As + r * 64 + ((chunk ^ (r & 7)) * 8));
      }
#pragma unroll
      for (int fn = 0; fn < 4; fn++) {
        int r = wn * 64 + fn * 16 + rl;
        bfr[fn] = *(const s16x8*)(Bs + r * 64 + ((chunk ^ (r & 7)) * 8));
      }
#pragma unroll
      for (int fm = 0; fm < 4; fm++)
#pragma unroll
        for (int fn = 0; fn < 4; fn++)
          acc[fm][fn] = __builtin_amdgcn_mfma_f32_16x16x32_bf16(af[fm], bfr[fn], acc[fm][fn], 0, 0, 0);
    }
    __syncthreads();
  }
  // epilogue: +bias, ->bf16. Q/K scatter to [h][b][s][e]; V directly transposed
  // to Vt [h][b][e][s] with ushort4-packed stores (j-quad = 4 consecutive s).
#pragma unroll
  for (int fn = 0; fn < 4; fn++) {
    int n = n0 + wn * 64 + fn * 16 + rl;
    int mat = n >> 10, h = (n >> 6) & 15, e = n & 63;
    const float* bias = (mat == 0) ? bq : (mat == 1) ? bk : bv;
    float bval = bias[h * 64 + e];
    if (mat == 2) {
#pragma unroll
      for (int fm = 0; fm < 4; fm++) {
        int sq = m0 + wm * 64 + fm * 16 + kg * 4;
        int bb = sq >> 10, s = sq & 1023;
        ushort4 o;
        o.x = f2b(acc[fm][fn][0] + bval);
        o.y = f2b(acc[fm][fn][1] + bval);
        o.z = f2b(acc[fm][fn][2] + bval);
        o.w = f2b(acc[fm][fn][3] + bval);
        *(ushort4*)(Vt + ((size_t)((h * B_ + bb) * E_ + e) << 10) + s) = o;
      }
    } else {
      u16* dst = (mat == 0) ? Qb : Kb;
#pragma unroll
      for (int fm = 0; fm < 4; fm++)
#pragma unroll
        for (int j = 0; j < 4; j++) {
          int m = m0 + wm * 64 + fm * 16 + kg * 4 + j;
          int bb = m >> 10, s = m & 1023;
          dst[(size_t)((h * B_ + bb) * S_ + s) * E_ + e] = f2b(acc[fm][fn][j] + bval);
        }
    }
  }
}

// ---------------- kernel 3: fused attention, K/V LDS-resident ----------------
__global__ __launch_bounds__(512, 2) void f_attn(
    const u16* __restrict__ Qb, const u16* __restrict__ Kb, const u16* __restrict__ Vt,
    const float* __restrict__ x, float* __restrict__ att, float* __restrict__ out) {
  __shared__ u16 Qlds[64 * 64];        // 8 KB
  __shared__ u16 KV[1024 * 64];        // 128 KB: K panel, later V^T panel
  __shared__ u16 Ab[2][64 * 64];       // 16 KB att-bf16 chunk dbuf
  __shared__ float red[3][64][4];      // 3 KB cross-wave reduce

  int p = blockIdx.x;
  int L = (p & 7) * 256 + (p >> 3);    // XCD-chunked: 16 consecutive hb per XCD
  int hb = L >> 4, mblk = L & 15;
  int m0 = mblk * 64;
  int tid = threadIdx.x, l = tid & 63, w = tid >> 6;  // 8 waves
  int rl = l & 15, kg = l >> 4;
  int rh = w >> 2, cq = w & 3;   // QK: row-half, col-quarter

  const u16* Qp = Qb + (size_t)hb * (S_ * E_) + (size_t)m0 * E_;
  const u16* Kp = Kb + (size_t)hb * (S_ * E_);
  const u16* Vp = Vt + (size_t)hb * (S_ * E_);

  // ---- stage Q (64x64) + FULL K panel (1024x64) ----
  {
    int r = w * 8 + (l >> 3), c = (l & 7) ^ (r & 7);
    gload16(Qp + (size_t)r * E_ + c * 8, (char*)Qlds + w * 1024);
  }
#pragma unroll
  for (int i = 0; i < 16; i++) {
    int ci = w * 16 + i;
    int r = ci * 8 + (l >> 3), c = (l & 7) ^ (r & 7);
    gload16(Kp + (size_t)r * E_ + c * 8, (char*)KV + ci * 1024);
  }
  __syncthreads();   // full drain required: K,Q must be in LDS

  s16x8 af[2][2];
#pragma unroll
  for (int fm = 0; fm < 2; fm++)
#pragma unroll
    for (int kk = 0; kk < 2; kk++) {
      int r = rh * 32 + fm * 16 + rl, ch = kk * 4 + kg;
      af[fm][kk] = *(const s16x8*)((const char*)Qlds + r * 128 + ((ch ^ (r & 7)) * 16));
    }

  f32x4 acc[2][16];
#pragma unroll
  for (int fm = 0; fm < 2; fm++)
#pragma unroll
    for (int ct = 0; ct < 16; ct++)
#pragma unroll
      for (int j = 0; j < 4; j++) acc[fm][ct][j] = 0.f;

  // ---- QK^T: no barriers, K resident ----
#pragma unroll
  for (int ct = 0; ct < 16; ct++) {
    s16x8 bf[2];
#pragma unroll
    for (int kk = 0; kk < 2; kk++) {
      int r = ct * 64 + cq * 16 + rl, ch = kk * 4 + kg;
      bf[kk] = *(const s16x8*)((const char*)KV + r * 128 + ((ch ^ (r & 7)) * 16));
    }
#pragma unroll
    for (int fm = 0; fm < 2; fm++)
#pragma unroll
      for (int kk = 0; kk < 2; kk++)
        acc[fm][ct] = __builtin_amdgcn_mfma_f32_16x16x32_bf16(af[fm][kk], bf[kk], acc[fm][ct], 0, 0, 0);
  }
  __syncthreads();   // all K reads done -> safe to overwrite KV with V

  // ---- issue FULL V^T panel load (stays in flight through softmax) ----
#pragma unroll
  for (int i = 0; i < 16; i++) {
    int ci = w * 16 + i;
    int e = ci >> 1, hf = ci & 1;
    int c = ((hf * 64 + l) & ~7) | ((l & 7) ^ (e & 7));
    gload16(Vp + (size_t)e * S_ + c * 8, (char*)KV + e * 2048 + hf * 1024);
  }

  // ---- softmax (scale 1/32 folded into exp); lgkm-only barriers keep V in flight ----
  float mx[2][4], Z[2][4], Z2[2][4];
#pragma unroll
  for (int fm = 0; fm < 2; fm++)
#pragma unroll
    for (int j = 0; j < 4; j++) {
      float m = acc[fm][0][j];
#pragma unroll
      for (int ct = 1; ct < 16; ct++) m = fmaxf(m, acc[fm][ct][j]);
#pragma unroll
      for (int off = 8; off >= 1; off >>= 1) m = fmaxf(m, __shfl_xor(m, off));
      mx[fm][j] = m;
    }
  if (rl == 0) {
#pragma unroll
    for (int fm = 0; fm < 2; fm++)
#pragma unroll
      for (int j = 0; j < 4; j++) red[0][rh * 32 + fm * 16 + kg * 4 + j][cq] = mx[fm][j];
  }
  BARL();
#pragma unroll
  for (int fm = 0; fm < 2; fm++)
#pragma unroll
    for (int j = 0; j < 4; j++) {
      f32x4 r4 = *(const f32x4*)&red[0][rh * 32 + fm * 16 + kg * 4 + j][0];
      mx[fm][j] = fmaxf(fmaxf(r4[0], r4[1]), fmaxf(r4[2], r4[3]));
    }
#pragma unroll
  for (int fm = 0; fm < 2; fm++)
#pragma unroll
    for (int j = 0; j < 4; j++) {
      float s = 0.f;
#pragma unroll
      for (int ct = 0; ct < 16; ct++) {
        float e = __expf((acc[fm][ct][j] - mx[fm][j]) * 0.03125f);
        acc[fm][ct][j] = e;
        s += e;
      }
#pragma unroll
      for (int off = 8; off >= 1; off >>= 1) s += __shfl_xor(s, off);
      Z[fm][j] = s;
    }
  if (rl == 0) {
#pragma unroll
    for (int fm = 0; fm < 2; fm++)
#pragma unroll
      for (int j = 0; j < 4; j++) red[1][rh * 32 + fm * 16 + kg * 4 + j][cq] = Z[fm][j];
  }
  BARL();
#pragma unroll
  for (int fm = 0; fm < 2; fm++)
#pragma unroll
    for (int j = 0; j < 4; j++) {
      f32x4 r4 = *(const f32x4*)&red[1][rh * 32 + fm * 16 + kg * 4 + j][0];
      Z[fm][j] = r4[0] + r4[1] + r4[2] + r4[3];
    }
  // threshold: keep e >= 0.001*Z (<=> p >= 0.001), re-sum survivors
#pragma unroll
  for (int fm = 0; fm < 2; fm++)
#pragma unroll
    for (int j = 0; j < 4; j++) {
      float thr = 0.001f * Z[fm][j];
      float s = 0.f;
#pragma unroll
      for (int ct = 0; ct < 16; ct++) {
        float e = acc[fm][ct][j];
        e = (e >= thr) ? e : 0.f;
        acc[fm][ct][j] = e;
        s += e;
      }
#pragma unroll
      for (int off = 8; off >= 1; off >>= 1) s += __shfl_xor(s, off);
      Z2[fm][j] = s;
    }
  if (rl == 0) {
#pragma unroll
    for (int fm = 0; fm < 2; fm++)
#pragma unroll
      for (int j = 0; j < 4; j++) red[2][rh * 32 + fm * 16 + kg * 4 + j][cq] = Z2[fm][j];
  }
  BARL();
#pragma unroll
  for (int fm = 0; fm < 2; fm++)
#pragma unroll
    for (int j = 0; j < 4; j++) {
      f32x4 r4 = *(const f32x4*)&red[2][rh * 32 + fm * 16 + kg * 4 + j][0];
      float z2 = r4[0] + r4[1] + r4[2] + r4[3];
      float inv = 1.f / (z2 + 1e-12f * Z[fm][j]);  // == p/(sum_kept_p + 1e-12)
#pragma unroll
      for (int ct = 0; ct < 16; ct++) acc[fm][ct][j] *= inv;
    }

  // ---- retire own V loads (cross-wave ordering via first PV barrier) ----
  asm volatile("s_waitcnt vmcnt(0)" ::: "memory");
  __builtin_amdgcn_sched_barrier(0);

  // ---- att fp32 stores: issued now, fly under the whole PV loop, never waited ----
  float* attp = att + ((size_t)hb << 20) + ((size_t)m0 << 10);
#pragma unroll
  for (int fm = 0; fm < 2; fm++)
#pragma unroll
    for (int j = 0; j < 4; j++) {
      int m = rh * 32 + fm * 16 + kg * 4 + j;
#pragma unroll
      for (int ct = 0; ct < 16; ct++)
        attp[((size_t)m << 10) + ct * 64 + cq * 16 + rl] = acc[fm][ct][j];
    }

  // ---- PV, software-pipelined: write Ab[ct+1] between ct's ds_reads and MFMAs ----
  int mh2 = w >> 1, nh2 = w & 1;
  f32x4 acc2[2];
#pragma unroll
  for (int fn = 0; fn < 2; fn++)
#pragma unroll
    for (int j = 0; j < 4; j++) acc2[fn][j] = 0.f;

  // prologue: publish chunk 0
#pragma unroll
  for (int fm = 0; fm < 2; fm++)
#pragma unroll
    for (int j = 0; j < 4; j++) {
      int m = rh * 32 + fm * 16 + kg * 4 + j;
      int tl = cq * 16 + rl;
      *(u16*)((char*)Ab[0] + m * 128 + (((tl >> 3) ^ (m & 7)) * 16) + (tl & 7) * 2)
          = f2b(acc[fm][0][j]);
    }
  BARL();

#pragma unroll
  for (int ct = 0; ct < 16; ct++) {
    s16x8 a2[2], b2[2][2];
#pragma unroll
    for (int kk = 0; kk < 2; kk++) {
      int ch = kk * 4 + kg;
      int rA = mh2 * 16 + rl;
      a2[kk] = *(const s16x8*)((const char*)Ab[ct & 1] + rA * 128 + ((ch ^ (rA & 7)) * 16));
#pragma unroll
      for (int fn = 0; fn < 2; fn++) {
        int e = nh2 * 32 + fn * 16 + rl;
        b2[fn][kk] = *(const s16x8*)((const char*)KV + e * 2048 + ct * 128 + ((ch ^ (e & 7)) * 16));
      }
    }
    if (ct < 15) {  // stage next chunk into the other buffer (reads above target ct&1)
#pragma unroll
      for (int fm = 0; fm < 2; fm++)
#pragma unroll
        for (int j = 0; j < 4; j++) {
          int m = rh * 32 + fm * 16 + kg * 4 + j;
          int tl = cq * 16 + rl;
          *(u16*)((char*)Ab[(ct + 1) & 1] + m * 128 + (((tl >> 3) ^ (m & 7)) * 16) + (tl & 7) * 2)
              = f2b(acc[fm][ct + 1][j]);
        }
    }
    __builtin_amdgcn_s_setprio(1);
#pragma unroll
    for (int fn = 0; fn < 2; fn++)
#pragma unroll
      for (int kk = 0; kk < 2; kk++)
        acc2[fn] = __builtin_amdgcn_mfma_f32_16x16x32_bf16(a2[kk], b2[fn][kk], acc2[fn], 0, 0, 0);
    __builtin_amdgcn_s_setprio(0);
    BARL();
  }

  // ---- epilogue: out = x + latent ----
  int h = hb >> 3, bb = hb & 7;
#pragma unroll
  for (int fn = 0; fn < 2; fn++)
#pragma unroll
    for (int j = 0; j < 4; j++) {
      int m = m0 + mh2 * 16 + kg * 4 + j;
      int e = h * 64 + nh2 * 32 + fn * 16 + rl;
      size_t idx = (((size_t)bb * S_ + m) << 10) + e;
      out[idx] = x[idx] + acc2[fn][j];
    }
}

extern "C" void kernel_launch(void* const* d_in, const int* in_sizes, int n_in,
                              void* d_out, int out_size, void* d_ws, size_t ws_size,
                              hipStream_t stream) {
  const float* x  = (const float*)d_in[0];
  const float* Wq = (const float*)d_in[1];
  const float* bq = (const float*)d_in[2];
  const float* Wk = (const float*)d_in[3];
  const float* bk = (const float*)d_in[4];
  const float* Wv = (const float*)d_in[5];
  const float* bv = (const float*)d_in[6];
  float* xres = (float*)d_out;
  float* att  = xres + (size_t)B_ * S_ * D_;

  char* ws = (char*)d_ws;
  u16* xb  = (u16*)(ws);                  // 16 MB
  u16* wbt = (u16*)(ws + 16777216);       //  6 MB
  u16* Qb  = (u16*)(ws + 23068672);       // 16 MB
  u16* Kb  = (u16*)(ws + 39845888);       // 16 MB
  u16* Vt  = (u16*)(ws + 56623104);       // 16 MB, [h][b][e][s] written by k_qkv

  k_prep  <<<dim3(4864), dim3(256), 0, stream>>>(x, xb, Wq, Wk, Wv, wbt);
  k_qkv   <<<dim3(1536), dim3(256), 0, stream>>>(xb, wbt, bq, bk, bv, Qb, Kb, Vt);
  f_attn  <<<dim3(2048), dim3(512), 0, stream>>>(Qb, Kb, Vt, x, att, xres);
}